// Round 8
// baseline (816.177 us; speedup 1.0000x reference)
//
#include <hip/hip_runtime.h>
#include <cstdint>
#include <cstddef>

#define NN 50000
#define NE 800000
#define HD 64
#define SB 49  // scan blocks = ceil(50000/1024)

// ---------------- CSR build: histogram ----------------
__global__ void k_hist(const int* __restrict__ ei, int* __restrict__ cnt) {
    int e = blockIdx.x * blockDim.x + threadIdx.x;
    if (e < NE) atomicAdd(&cnt[ei[NE + e]], 1);
}

// ------- hierarchical scan, phase 1: per-block local exclusive scan -------
__global__ __launch_bounds__(256) void k_scan1(const int* __restrict__ cnt,
                                               int* __restrict__ row_start,
                                               int* __restrict__ bsum) {
    __shared__ int ssum[256];
    const int tid = threadIdx.x, b = blockIdx.x;
    const int i0 = b * 1024 + tid * 4;
    int c0 = 0, c1 = 0, c2 = 0, c3 = 0;
    if (i0 + 3 < NN) {
        const int4 c = *(const int4*)(cnt + i0);
        c0 = c.x; c1 = c.y; c2 = c.z; c3 = c.w;
    } else {
        if (i0 + 0 < NN) c0 = cnt[i0 + 0];
        if (i0 + 1 < NN) c1 = cnt[i0 + 1];
        if (i0 + 2 < NN) c2 = cnt[i0 + 2];
        if (i0 + 3 < NN) c3 = cnt[i0 + 3];
    }
    ssum[tid] = c0 + c1 + c2 + c3;
    __syncthreads();
    for (int off = 1; off < 256; off <<= 1) {
        int v = (tid >= off) ? ssum[tid - off] : 0;
        __syncthreads();
        ssum[tid] += v;
        __syncthreads();
    }
    int ex = (tid == 0) ? 0 : ssum[tid - 1];
    if (i0 + 0 < NN) row_start[i0 + 0] = ex;
    ex += c0;
    if (i0 + 1 < NN) row_start[i0 + 1] = ex;
    ex += c1;
    if (i0 + 2 < NN) row_start[i0 + 2] = ex;
    ex += c2;
    if (i0 + 3 < NN) row_start[i0 + 3] = ex;
    if (tid == 255) bsum[b] = ssum[255];
}

// ------- scan phase 2: scan the 49 block sums -------
__global__ __launch_bounds__(64) void k_scan2(const int* __restrict__ bsum,
                                              int* __restrict__ boff,
                                              int* __restrict__ row_start) {
    __shared__ int s[64];
    const int t = threadIdx.x;
    s[t] = (t < SB) ? bsum[t] : 0;
    __syncthreads();
    for (int off = 1; off < 64; off <<= 1) {
        int v = (t >= off) ? s[t - off] : 0;
        __syncthreads();
        s[t] += v;
        __syncthreads();
    }
    if (t < SB) boff[t] = (t == 0) ? 0 : s[t - 1];
    if (t == 0) row_start[NN] = s[SB - 1];  // = NE
}

// ------- scan phase 3: add block offsets; init cur = row_start -------
__global__ __launch_bounds__(256) void k_scan3(int* __restrict__ row_start,
                                               const int* __restrict__ boff,
                                               int* __restrict__ cur) {
    const int b = blockIdx.x;
    const int i0 = b * 1024 + threadIdx.x * 4;
    const int o = boff[b];
#pragma unroll
    for (int k = 0; k < 4; ++k) {
        int i = i0 + k;
        if (i < NN) {
            int v = row_start[i] + o;
            row_start[i] = v;
            cur[i] = v;
        }
    }
}

// ------- CSR scatter: row = [e0..e3, e4, src_byteoff, 0, 0] dst-sorted -------
__global__ void k_scatter(const int* __restrict__ ei, const float* __restrict__ ea,
                          int* __restrict__ cur, float* __restrict__ e5s) {
    int e = blockIdx.x * blockDim.x + threadIdx.x;
    if (e < NE) {
        int d = ei[NE + e];
        int pos = atomicAdd(&cur[d], 1);
        float4 lo;
        lo.x = __logf(ea[e * 5 + 0] + 1.f);
        lo.y = __logf(ea[e * 5 + 1] + 1.f);
        lo.z = __logf(ea[e * 5 + 2] + 1.f);
        lo.w = __logf(ea[e * 5 + 3] + 1.f);
        float4 hi;
        hi.x = __logf(ea[e * 5 + 4] + 1.f);
        hi.y = __int_as_float(ei[e] << 9);  // byte offset into kv (src*512)
        hi.z = 0.f;
        hi.w = 0.f;
        *(float4*)(e5s + (size_t)pos * 8) = lo;
        *(float4*)(e5s + (size_t)pos * 8 + 4) = hi;
    }
}

// ------- fused 4-matrix GEMM, DIN=64: LDS x-tile shared by 4 waves -------
// Wave w computes matrix w (0=q,1=k,2=v,3=s); lane = out col; weights in
// 64 VGPRs. Per tile: 16 nodes (4 KB) staged coalesced (1 float4/thread),
// then broadcast ds_read_b128 (same-address -> free) + 4 FMA per quad.
__global__ __launch_bounds__(256, 4) void k_qkvs64(
    const float* __restrict__ h,
    const float* __restrict__ Wq, const float* __restrict__ Bq,
    const float* __restrict__ Wk, const float* __restrict__ Bk,
    const float* __restrict__ Wv, const float* __restrict__ Bv,
    const float* __restrict__ Ws, const float* __restrict__ Bs,
    float* __restrict__ qb, float* __restrict__ kvb, float* __restrict__ sb) {
    __shared__ float xs[1024];
    const int lane = threadIdx.x & 63;
    const int w = threadIdx.x >> 6;
    const float* W = (w == 0) ? Wq : (w == 1) ? Wk : (w == 2) ? Wv : Ws;
    const float* B = (w == 0) ? Bq : (w == 1) ? Bk : (w == 2) ? Bv : Bs;
    float* outp = (w == 0) ? qb : (w == 1) ? kvb : (w == 2) ? (kvb + 64) : sb;
    const int ldo = (w == 1 || w == 2) ? 128 : 64;
    float wr[64];
#pragma unroll
    for (int j = 0; j < 64; ++j) wr[j] = W[j * 64 + lane];
    const float bias = B[lane];
    const int ntile = NN / 16;  // 3125
    for (int tile = blockIdx.x; tile < ntile; tile += gridDim.x) {
        __syncthreads();  // protect previous tile's LDS from overwrite
        *(float4*)&xs[threadIdx.x * 4] =
            *(const float4*)(h + (size_t)tile * 1024 + threadIdx.x * 4);
        __syncthreads();
        const int nbase = tile * 16;
        for (int nq = 0; nq < 4; ++nq) {
            float acc[4] = {bias, bias, bias, bias};
#pragma unroll
            for (int jq = 0; jq < 16; ++jq) {
#pragma unroll
                for (int n = 0; n < 4; ++n) {
                    const float4 xv = *(const float4*)&xs[(nq * 4 + n) * 64 + jq * 4];
                    acc[n] = fmaf(xv.x, wr[jq * 4 + 0], acc[n]);
                    acc[n] = fmaf(xv.y, wr[jq * 4 + 1], acc[n]);
                    acc[n] = fmaf(xv.z, wr[jq * 4 + 2], acc[n]);
                    acc[n] = fmaf(xv.w, wr[jq * 4 + 3], acc[n]);
                }
            }
#pragma unroll
            for (int n = 0; n < 4; ++n)
                outp[(size_t)(nbase + nq * 4 + n) * ldo + lane] = acc[n];
        }
    }
}

// ------- fused 4-matrix GEMM, DIN=10 (layer 1, log1p fused at staging) -------
// 64 nodes/tile (640 floats LDS). grid covers all tiles directly.
__global__ __launch_bounds__(256, 4) void k_qkvs10(
    const float* __restrict__ x,
    const float* __restrict__ Wq, const float* __restrict__ Bq,
    const float* __restrict__ Wk, const float* __restrict__ Bk,
    const float* __restrict__ Wv, const float* __restrict__ Bv,
    const float* __restrict__ Ws, const float* __restrict__ Bs,
    float* __restrict__ qb, float* __restrict__ kvb, float* __restrict__ sb) {
    __shared__ float xs[640];
    const int lane = threadIdx.x & 63;
    const int w = threadIdx.x >> 6;
    const float* W = (w == 0) ? Wq : (w == 1) ? Wk : (w == 2) ? Wv : Ws;
    const float* B = (w == 0) ? Bq : (w == 1) ? Bk : (w == 2) ? Bv : Bs;
    float* outp = (w == 0) ? qb : (w == 1) ? kvb : (w == 2) ? (kvb + 64) : sb;
    const int ldo = (w == 1 || w == 2) ? 128 : 64;
    float wr[10];
#pragma unroll
    for (int j = 0; j < 10; ++j) wr[j] = W[j * 64 + lane];
    const float bias = B[lane];
    const int tile = blockIdx.x;
    const int fbase = tile * 640;
    const int fcnt = min(640, NN * 10 - fbase);
    if (threadIdx.x * 4 < fcnt) {
        float4 v = *(const float4*)(x + (size_t)fbase + threadIdx.x * 4);
        v.x = __logf(v.x + 1.f);
        v.y = __logf(v.y + 1.f);
        v.z = __logf(v.z + 1.f);
        v.w = __logf(v.w + 1.f);
        *(float4*)&xs[threadIdx.x * 4] = v;
    }
    __syncthreads();
    const int nbase = tile * 64;
    const int nodes = min(64, NN - nbase);
    for (int n = 0; n < nodes; ++n) {
        float acc = bias;
#pragma unroll
        for (int j = 0; j < 10; ++j) acc = fmaf(xs[n * 10 + j], wr[j], acc);
        outp[(size_t)(nbase + n) * ldo + lane] = acc;
    }
}

// ---------------- per-dst-node online-softmax aggregation ----------------
// One wave per dst node; 4 edges/iter; g = lane>>4 (edge slot), t = lane&15.
// PER-GROUP softmax state (m,l,acc,a5) -> zero cross-group shfls in the loop;
// flash-style 4-way state merge at the end. 2 exps/iter.
// e5 rows prefetched 2 iters ahead so the kv gather src is always resident.
__global__ __launch_bounds__(256) void k_agg(
    const float* __restrict__ q, const float* __restrict__ kv,
    const float* __restrict__ sk, const float* __restrict__ e5s,
    const float* __restrict__ wE, const int* __restrict__ row_start,
    float* __restrict__ hout) {
    const int lane = threadIdx.x & 63;
    const int g = lane >> 4, t = lane & 15;
    const int node = __builtin_amdgcn_readfirstlane(blockIdx.x * 4 + (threadIdx.x >> 6));
    if (node >= NN) return;
    const int beg = row_start[node], end = row_start[node + 1];
    if (beg == end) {
        if (g == 0)
            *(float4*)(hout + (size_t)node * 64 + t * 4) =
                *(const float4*)(sk + (size_t)node * 64 + t * 4);
        return;
    }
    const float4 q4 = *(const float4*)(q + (size_t)node * 64 + t * 4);
    // g5[c] = dot64(q, wE row c) via in-group butterfly (identical in all groups)
    float g5[5];
#pragma unroll
    for (int c = 0; c < 5; ++c) {
        const float4 w4 = *(const float4*)(wE + c * 64 + t * 4);
        float d = q4.x * w4.x;
        d = fmaf(q4.y, w4.y, d);
        d = fmaf(q4.z, w4.z, d);
        d = fmaf(q4.w, w4.w, d);
        d += __shfl_xor(d, 1);
        d += __shfl_xor(d, 2);
        d += __shfl_xor(d, 4);
        d += __shfl_xor(d, 8);
        g5[c] = d;
    }
    // per-group online-softmax state
    float m = -1e30f, l = 0.f;
    float4 accv = {0.f, 0.f, 0.f, 0.f};
    float a50 = 0.f, a51 = 0.f, a52 = 0.f, a53 = 0.f, a54 = 0.f;
    const char* kvc = (const char*)kv;
    // pipeline preamble: e5 2-deep, kv 1-deep
    const int pp0 = (beg + g < end) ? beg + g : beg;
    float4 e0lo = *(const float4*)(e5s + (size_t)pp0 * 8);
    float4 e0hi = *(const float4*)(e5s + (size_t)pp0 * 8 + 4);
    const int p1x = beg + 4 + g;
    const int pp1 = (p1x < end) ? p1x : beg;
    float4 e1lo = *(const float4*)(e5s + (size_t)pp1 * 8);
    float4 e1hi = *(const float4*)(e5s + (size_t)pp1 * 8 + 4);
    const float* kp0 = (const float*)(kvc + (size_t)(unsigned)__float_as_int(e0hi.y)) + t * 4;
    float4 k4 = *(const float4*)(kp0);
    float4 v4 = *(const float4*)(kp0 + 64);
    for (int p = beg; p < end; p += 4) {
        // e5 prefetch for iter p+8 (sequential, L2-friendly)
        const int nx = p + 8 + g;
        const int npp = (nx < end) ? nx : beg;
        const float4 nlo = *(const float4*)(e5s + (size_t)npp * 8);
        const float4 nhi = *(const float4*)(e5s + (size_t)npp * 8 + 4);
        // kv gather for iter p+4 (e1 landed one iter ago -> no stall on src)
        const float* kpn =
            (const float*)(kvc + (size_t)(unsigned)__float_as_int(e1hi.y)) + t * 4;
        const float4 nk4 = *(const float4*)(kpn);
        const float4 nv4 = *(const float4*)(kpn + 64);
        // compute current edge (k4/v4 gathered last iter)
        const bool act = (p + g) < end;
        float d = q4.x * k4.x;
        d = fmaf(q4.y, k4.y, d);
        d = fmaf(q4.z, k4.z, d);
        d = fmaf(q4.w, k4.w, d);
        d += __shfl_xor(d, 1);
        d += __shfl_xor(d, 2);
        d += __shfl_xor(d, 4);
        d += __shfl_xor(d, 8);
        float d5 = g5[0] * e0lo.x;
        d5 = fmaf(g5[1], e0lo.y, d5);
        d5 = fmaf(g5[2], e0lo.z, d5);
        d5 = fmaf(g5[3], e0lo.w, d5);
        d5 = fmaf(g5[4], e0hi.x, d5);
        const float la = act ? (d + d5) * 0.125f : -1e30f;
        const float nm = fmaxf(m, la);
        const float scl = __expf(m - nm);
        const float pa = __expf(la - nm);
        l = fmaf(l, scl, pa);
        accv.x = fmaf(accv.x, scl, pa * v4.x);
        accv.y = fmaf(accv.y, scl, pa * v4.y);
        accv.z = fmaf(accv.z, scl, pa * v4.z);
        accv.w = fmaf(accv.w, scl, pa * v4.w);
        a50 = fmaf(a50, scl, pa * e0lo.x);
        a51 = fmaf(a51, scl, pa * e0lo.y);
        a52 = fmaf(a52, scl, pa * e0lo.z);
        a53 = fmaf(a53, scl, pa * e0lo.w);
        a54 = fmaf(a54, scl, pa * e0hi.x);
        m = nm;
        // rotate pipeline
        e0lo = e1lo;
        e0hi = e1hi;
        e1lo = nlo;
        e1hi = nhi;
        k4 = nk4;
        v4 = nv4;
    }
    // ---- merge the 4 per-group states (flash-style) ----
    float M = fmaxf(m, __shfl_xor(m, 16));
    M = fmaxf(M, __shfl_xor(M, 32));
    const float f = __expf(m - M);  // 0 for never-active groups (m=-1e30)
    float lz = l * f;
    lz += __shfl_xor(lz, 16);
    lz += __shfl_xor(lz, 32);
    accv.x *= f;
    accv.y *= f;
    accv.z *= f;
    accv.w *= f;
    a50 *= f;
    a51 *= f;
    a52 *= f;
    a53 *= f;
    a54 *= f;
#pragma unroll
    for (int s = 16; s <= 32; s <<= 1) {
        accv.x += __shfl_xor(accv.x, s);
        accv.y += __shfl_xor(accv.y, s);
        accv.z += __shfl_xor(accv.z, s);
        accv.w += __shfl_xor(accv.w, s);
        a50 += __shfl_xor(a50, s);
        a51 += __shfl_xor(a51, s);
        a52 += __shfl_xor(a52, s);
        a53 += __shfl_xor(a53, s);
        a54 += __shfl_xor(a54, s);
    }
    // fold edge-feature accumulator back through wE; add skip
    float4 t4 = accv;
    {
        const float4 w0 = *(const float4*)(wE + 0 * 64 + t * 4);
        const float4 w1 = *(const float4*)(wE + 1 * 64 + t * 4);
        const float4 w2 = *(const float4*)(wE + 2 * 64 + t * 4);
        const float4 w3 = *(const float4*)(wE + 3 * 64 + t * 4);
        const float4 w4r = *(const float4*)(wE + 4 * 64 + t * 4);
        t4.x = fmaf(a50, w0.x, t4.x);
        t4.y = fmaf(a50, w0.y, t4.y);
        t4.z = fmaf(a50, w0.z, t4.z);
        t4.w = fmaf(a50, w0.w, t4.w);
        t4.x = fmaf(a51, w1.x, t4.x);
        t4.y = fmaf(a51, w1.y, t4.y);
        t4.z = fmaf(a51, w1.z, t4.z);
        t4.w = fmaf(a51, w1.w, t4.w);
        t4.x = fmaf(a52, w2.x, t4.x);
        t4.y = fmaf(a52, w2.y, t4.y);
        t4.z = fmaf(a52, w2.z, t4.z);
        t4.w = fmaf(a52, w2.w, t4.w);
        t4.x = fmaf(a53, w3.x, t4.x);
        t4.y = fmaf(a53, w3.y, t4.y);
        t4.z = fmaf(a53, w3.z, t4.z);
        t4.w = fmaf(a53, w3.w, t4.w);
        t4.x = fmaf(a54, w4r.x, t4.x);
        t4.y = fmaf(a54, w4r.y, t4.y);
        t4.z = fmaf(a54, w4r.z, t4.z);
        t4.w = fmaf(a54, w4r.w, t4.w);
    }
    const float4 s4 = *(const float4*)(sk + (size_t)node * 64 + t * 4);
    const float rl = 1.f / lz;
    float4 o;
    o.x = fmaf(t4.x, rl, s4.x);
    o.y = fmaf(t4.y, rl, s4.y);
    o.z = fmaf(t4.z, rl, s4.z);
    o.w = fmaf(t4.w, rl, s4.w);
    if (g == 0) *(float4*)(hout + (size_t)node * 64 + t * 4) = o;
}

// ---------------- final linear HID -> 1 ----------------
__global__ __launch_bounds__(256) void k_final(const float* __restrict__ h,
                                               const float* __restrict__ lw,
                                               const float* __restrict__ lb,
                                               float* __restrict__ out) {
    const int lane = threadIdx.x & 63;
    int node = blockIdx.x * 4 + (threadIdx.x >> 6);
    if (node >= NN) return;
    float t = h[(size_t)node * 64 + lane] * lw[lane];
#pragma unroll
    for (int off = 32; off > 0; off >>= 1) t += __shfl_xor(t, off, 64);
    if (lane == 0) out[node] = t + lb[0];
}

extern "C" void kernel_launch(void* const* d_in, const int* in_sizes, int n_in,
                              void* d_out, int out_size, void* d_ws, size_t ws_size,
                              hipStream_t stream) {
    const float* x = (const float*)d_in[0];
    const int* ei = (const int*)d_in[1];
    const float* ea = (const float*)d_in[2];
    const float* w1q = (const float*)d_in[3];
    const float* b1q = (const float*)d_in[4];
    const float* w1k = (const float*)d_in[5];
    const float* b1k = (const float*)d_in[6];
    const float* w1v = (const float*)d_in[7];
    const float* b1v = (const float*)d_in[8];
    const float* w1e = (const float*)d_in[9];
    const float* w1s = (const float*)d_in[10];
    const float* b1s = (const float*)d_in[11];
    const float* wq = (const float*)d_in[12];
    const float* bq = (const float*)d_in[13];
    const float* wk = (const float*)d_in[14];
    const float* bk = (const float*)d_in[15];
    const float* wv = (const float*)d_in[16];
    const float* bv = (const float*)d_in[17];
    const float* we = (const float*)d_in[18];
    const float* ws = (const float*)d_in[19];
    const float* bs = (const float*)d_in[20];
    const float* lw = (const float*)d_in[21];
    const float* lb = (const float*)d_in[22];

    // ---- workspace carve (256B aligned), ~90 MB ----
    uintptr_t p = (uintptr_t)d_ws;
    auto alloc = [&](size_t bytes) -> void* {
        void* r = (void*)p;
        p += (bytes + 255) & ~(size_t)255;
        return r;
    };
    float* e5s = (float*)alloc((size_t)NE * 8 * 4);    // 25.6 MB, dst-sorted rows
    float* hb = (float*)alloc((size_t)NN * HD * 4);    // 12.8 MB
    float* kvb = (float*)alloc((size_t)NN * 128 * 4);  // 25.6 MB interleaved k|v
    float* qb = (float*)alloc((size_t)NN * HD * 4);
    float* sb = (float*)alloc((size_t)NN * HD * 4);
    int* row_start = (int*)alloc((size_t)(NN + 1) * 4);
    int* cnt = (int*)alloc((size_t)NN * 4);
    int* cur = (int*)alloc((size_t)NN * 4);
    int* bsum = (int*)alloc((size_t)SB * 4);
    int* boff = (int*)alloc((size_t)SB * 4);

    // ---- preprocess (once per call) ----
    hipMemsetAsync(cnt, 0, (size_t)NN * 4, stream);
    k_hist<<<(NE + 255) / 256, 256, 0, stream>>>(ei, cnt);
    k_scan1<<<SB, 256, 0, stream>>>(cnt, row_start, bsum);
    k_scan2<<<1, 64, 0, stream>>>(bsum, boff, row_start);
    k_scan3<<<SB, 256, 0, stream>>>(row_start, boff, cur);
    k_scatter<<<(NE + 255) / 256, 256, 0, stream>>>(ei, ea, cur, e5s);

    const int gg64 = 1563;              // DIN=64 GEMM grid (2 tiles/block)
    const int gg10 = (NN + 63) / 64;    // 782
    const int agg_grid = (NN + 3) / 4;  // 12500

    // ---- layer 1 (DIN=10, log1p fused) ----
    k_qkvs10<<<gg10, 256, 0, stream>>>(x, w1q, b1q, w1k, b1k, w1v, b1v, w1s, b1s,
                                       qb, kvb, sb);
    k_agg<<<agg_grid, 256, 0, stream>>>(qb, kvb, sb, e5s, w1e, row_start, hb);

    // ---- layers 2..6 (DIN=64) ----
    for (int i = 0; i < 5; ++i) {
        k_qkvs64<<<gg64, 256, 0, stream>>>(hb, wq + i * 4096, bq + i * 64,
                                           wk + i * 4096, bk + i * 64,
                                           wv + i * 4096, bv + i * 64,
                                           ws + i * 4096, bs + i * 64,
                                           qb, kvb, sb);
        k_agg<<<agg_grid, 256, 0, stream>>>(qb, kvb, sb, e5s, we + i * 320, row_start, hb);
    }

    // ---- final linear ----
    k_final<<<agg_grid, 256, 0, stream>>>(hb, lw, lb, (float*)d_out);
}

// Round 9
// 754.182 us; speedup vs baseline: 1.0822x; 1.0822x over previous
//
#include <hip/hip_runtime.h>
#include <cstdint>
#include <cstddef>

#define NN 50000
#define NE 800000
#define HD 64
#define SB 49  // scan blocks = ceil(50000/1024)

// ---------------- CSR build: histogram ----------------
__global__ void k_hist(const int* __restrict__ ei, int* __restrict__ cnt) {
    int e = blockIdx.x * blockDim.x + threadIdx.x;
    if (e < NE) atomicAdd(&cnt[ei[NE + e]], 1);
}

// ------- hierarchical scan, phase 1: per-block local exclusive scan -------
__global__ __launch_bounds__(256) void k_scan1(const int* __restrict__ cnt,
                                               int* __restrict__ row_start,
                                               int* __restrict__ bsum) {
    __shared__ int ssum[256];
    const int tid = threadIdx.x, b = blockIdx.x;
    const int i0 = b * 1024 + tid * 4;
    int c0 = 0, c1 = 0, c2 = 0, c3 = 0;
    if (i0 + 3 < NN) {
        const int4 c = *(const int4*)(cnt + i0);
        c0 = c.x; c1 = c.y; c2 = c.z; c3 = c.w;
    } else {
        if (i0 + 0 < NN) c0 = cnt[i0 + 0];
        if (i0 + 1 < NN) c1 = cnt[i0 + 1];
        if (i0 + 2 < NN) c2 = cnt[i0 + 2];
        if (i0 + 3 < NN) c3 = cnt[i0 + 3];
    }
    ssum[tid] = c0 + c1 + c2 + c3;
    __syncthreads();
    for (int off = 1; off < 256; off <<= 1) {
        int v = (tid >= off) ? ssum[tid - off] : 0;
        __syncthreads();
        ssum[tid] += v;
        __syncthreads();
    }
    int ex = (tid == 0) ? 0 : ssum[tid - 1];
    if (i0 + 0 < NN) row_start[i0 + 0] = ex;
    ex += c0;
    if (i0 + 1 < NN) row_start[i0 + 1] = ex;
    ex += c1;
    if (i0 + 2 < NN) row_start[i0 + 2] = ex;
    ex += c2;
    if (i0 + 3 < NN) row_start[i0 + 3] = ex;
    if (tid == 255) bsum[b] = ssum[255];
}

// ------- scan phase 2: scan the 49 block sums -------
__global__ __launch_bounds__(64) void k_scan2(const int* __restrict__ bsum,
                                              int* __restrict__ boff,
                                              int* __restrict__ row_start) {
    __shared__ int s[64];
    const int t = threadIdx.x;
    s[t] = (t < SB) ? bsum[t] : 0;
    __syncthreads();
    for (int off = 1; off < 64; off <<= 1) {
        int v = (t >= off) ? s[t - off] : 0;
        __syncthreads();
        s[t] += v;
        __syncthreads();
    }
    if (t < SB) boff[t] = (t == 0) ? 0 : s[t - 1];
    if (t == 0) row_start[NN] = s[SB - 1];  // = NE
}

// ------- scan phase 3: add block offsets; init cur = row_start -------
__global__ __launch_bounds__(256) void k_scan3(int* __restrict__ row_start,
                                               const int* __restrict__ boff,
                                               int* __restrict__ cur) {
    const int b = blockIdx.x;
    const int i0 = b * 1024 + threadIdx.x * 4;
    const int o = boff[b];
#pragma unroll
    for (int k = 0; k < 4; ++k) {
        int i = i0 + k;
        if (i < NN) {
            int v = row_start[i] + o;
            row_start[i] = v;
            cur[i] = v;
        }
    }
}

// ------- CSR scatter: row = [e0..e3, e4, src_byteoff, 0, 0] dst-sorted -------
__global__ void k_scatter(const int* __restrict__ ei, const float* __restrict__ ea,
                          int* __restrict__ cur, float* __restrict__ e5s) {
    int e = blockIdx.x * blockDim.x + threadIdx.x;
    if (e < NE) {
        int d = ei[NE + e];
        int pos = atomicAdd(&cur[d], 1);
        float4 lo;
        lo.x = __logf(ea[e * 5 + 0] + 1.f);
        lo.y = __logf(ea[e * 5 + 1] + 1.f);
        lo.z = __logf(ea[e * 5 + 2] + 1.f);
        lo.w = __logf(ea[e * 5 + 3] + 1.f);
        float4 hi;
        hi.x = __logf(ea[e * 5 + 4] + 1.f);
        hi.y = __int_as_float(ei[e] << 9);  // byte offset into kv (src*512)
        hi.z = 0.f;
        hi.w = 0.f;
        *(float4*)(e5s + (size_t)pos * 8) = lo;
        *(float4*)(e5s + (size_t)pos * 8 + 4) = hi;
    }
}

// ------- fused 4-matrix GEMM, DIN=64: wave-private LDS tiles, no syncs -------
// Wave w computes matrix w (0=q,1=k,2=v,3=s); lane = out col; 64 weight VGPRs.
// Each wave stages its own 4-node tile (1 KB, coalesced float4, wave-
// synchronous) then broadcast ds_read_b128 + FMA. The 4 waves of a block read
// the same h quad -> L1 hits for 3 of 4.
__global__ __launch_bounds__(256) void k_qkvs64(
    const float* __restrict__ h,
    const float* __restrict__ Wq, const float* __restrict__ Bq,
    const float* __restrict__ Wk, const float* __restrict__ Bk,
    const float* __restrict__ Wv, const float* __restrict__ Bv,
    const float* __restrict__ Ws, const float* __restrict__ Bs,
    float* __restrict__ qb, float* __restrict__ kvb, float* __restrict__ sb) {
    __shared__ float xs[4][256];
    const int lane = threadIdx.x & 63;
    const int w = threadIdx.x >> 6;
    const float* W = (w == 0) ? Wq : (w == 1) ? Wk : (w == 2) ? Wv : Ws;
    const float* B = (w == 0) ? Bq : (w == 1) ? Bk : (w == 2) ? Bv : Bs;
    float* outp = (w == 0) ? qb : (w == 1) ? kvb : (w == 2) ? (kvb + 64) : sb;
    const int ldo = (w == 1 || w == 2) ? 128 : 64;
    float wr[64];
#pragma unroll
    for (int j = 0; j < 64; ++j) wr[j] = W[j * 64 + lane];
    const float bias = B[lane];
    const int nquad = NN / 4;  // 12500
    for (int quad = blockIdx.x; quad < nquad; quad += gridDim.x) {
        *(float4*)&xs[w][lane * 4] =
            *(const float4*)(h + (size_t)quad * 256 + lane * 4);  // wave-sync staging
        float acc[4] = {bias, bias, bias, bias};
#pragma unroll
        for (int jq = 0; jq < 16; ++jq) {
#pragma unroll
            for (int n = 0; n < 4; ++n) {
                const float4 xv = *(const float4*)&xs[w][n * 64 + jq * 4];  // broadcast
                acc[n] = fmaf(xv.x, wr[jq * 4 + 0], acc[n]);
                acc[n] = fmaf(xv.y, wr[jq * 4 + 1], acc[n]);
                acc[n] = fmaf(xv.z, wr[jq * 4 + 2], acc[n]);
                acc[n] = fmaf(xv.w, wr[jq * 4 + 3], acc[n]);
            }
        }
#pragma unroll
        for (int n = 0; n < 4; ++n)
            outp[(size_t)(quad * 4 + n) * ldo + lane] = acc[n];
    }
}

// ------- fused 4-matrix GEMM, DIN=10 (layer 1, log1p fused at staging) -------
__global__ __launch_bounds__(256, 4) void k_qkvs10(
    const float* __restrict__ x,
    const float* __restrict__ Wq, const float* __restrict__ Bq,
    const float* __restrict__ Wk, const float* __restrict__ Bk,
    const float* __restrict__ Wv, const float* __restrict__ Bv,
    const float* __restrict__ Ws, const float* __restrict__ Bs,
    float* __restrict__ qb, float* __restrict__ kvb, float* __restrict__ sb) {
    __shared__ float xs[640];
    const int lane = threadIdx.x & 63;
    const int w = threadIdx.x >> 6;
    const float* W = (w == 0) ? Wq : (w == 1) ? Wk : (w == 2) ? Wv : Ws;
    const float* B = (w == 0) ? Bq : (w == 1) ? Bk : (w == 2) ? Bv : Bs;
    float* outp = (w == 0) ? qb : (w == 1) ? kvb : (w == 2) ? (kvb + 64) : sb;
    const int ldo = (w == 1 || w == 2) ? 128 : 64;
    float wr[10];
#pragma unroll
    for (int j = 0; j < 10; ++j) wr[j] = W[j * 64 + lane];
    const float bias = B[lane];
    const int tile = blockIdx.x;
    const int fbase = tile * 640;
    const int fcnt = min(640, NN * 10 - fbase);
    if (threadIdx.x * 4 < fcnt) {
        float4 v = *(const float4*)(x + (size_t)fbase + threadIdx.x * 4);
        v.x = __logf(v.x + 1.f);
        v.y = __logf(v.y + 1.f);
        v.z = __logf(v.z + 1.f);
        v.w = __logf(v.w + 1.f);
        *(float4*)&xs[threadIdx.x * 4] = v;
    }
    __syncthreads();
    const int nbase = tile * 64;
    const int nodes = min(64, NN - nbase);
    for (int n = 0; n < nodes; ++n) {
        float acc = bias;
#pragma unroll
        for (int j = 0; j < 10; ++j) acc = fmaf(xs[n * 10 + j], wr[j], acc);
        outp[(size_t)(nbase + n) * ldo + lane] = acc;
    }
}

// ---------------- per-dst-node online-softmax aggregation ----------------
// One wave per dst node; 4 edges/iter; g = lane>>4 (edge slot), t = lane&15.
// Per-group softmax state + flash merge (R6 structure). NEW: depth-2 software
// pipeline -- e5 rows 3 iters ahead, kv gathers issued 2 iters ahead of use,
// doubling the gather-latency budget. 0.125 folded into q at load.
// FINAL: fold the output linear (h . lw + lb) into the epilogue.
template <bool FINAL>
__global__ __launch_bounds__(256) void k_agg(
    const float* __restrict__ q, const float* __restrict__ kv,
    const float* __restrict__ sk, const float* __restrict__ e5s,
    const float* __restrict__ wE, const int* __restrict__ row_start,
    float* __restrict__ hout, const float* __restrict__ lw, const float* lb) {
    const int lane = threadIdx.x & 63;
    const int g = lane >> 4, t = lane & 15;
    const int node = __builtin_amdgcn_readfirstlane(blockIdx.x * 4 + (threadIdx.x >> 6));
    if (node >= NN) return;
    const int beg = row_start[node], end = row_start[node + 1];
    if (beg == end) {
        const float4 s4 = *(const float4*)(sk + (size_t)node * 64 + t * 4);
        if (FINAL) {
            const float4 lw4 = *(const float4*)(lw + t * 4);
            float r = s4.x * lw4.x;
            r = fmaf(s4.y, lw4.y, r);
            r = fmaf(s4.z, lw4.z, r);
            r = fmaf(s4.w, lw4.w, r);
            r += __shfl_xor(r, 1);
            r += __shfl_xor(r, 2);
            r += __shfl_xor(r, 4);
            r += __shfl_xor(r, 8);
            if (lane == 0) hout[node] = r + lb[0];
        } else if (g == 0) {
            *(float4*)(hout + (size_t)node * 64 + t * 4) = s4;
        }
        return;
    }
    float4 q4 = *(const float4*)(q + (size_t)node * 64 + t * 4);
    q4.x *= 0.125f;
    q4.y *= 0.125f;
    q4.z *= 0.125f;
    q4.w *= 0.125f;
    // g5[c] = dot64(q*0.125, wE row c) via in-group butterfly
    float g5[5];
#pragma unroll
    for (int c = 0; c < 5; ++c) {
        const float4 w4 = *(const float4*)(wE + c * 64 + t * 4);
        float d = q4.x * w4.x;
        d = fmaf(q4.y, w4.y, d);
        d = fmaf(q4.z, w4.z, d);
        d = fmaf(q4.w, w4.w, d);
        d += __shfl_xor(d, 1);
        d += __shfl_xor(d, 2);
        d += __shfl_xor(d, 4);
        d += __shfl_xor(d, 8);
        g5[c] = d;
    }
    // per-group online-softmax state
    float m = -1e30f, l = 0.f;
    float4 accv = {0.f, 0.f, 0.f, 0.f};
    float a50 = 0.f, a51 = 0.f, a52 = 0.f, a53 = 0.f, a54 = 0.f;
    const char* kvc = (const char*)kv;
    // pipeline preamble: e5 3-deep, kv 2-deep
    const int i0x = beg + g;
    const int i0 = (i0x < end) ? i0x : beg;
    float4 e0lo = *(const float4*)(e5s + (size_t)i0 * 8);
    float2 e0hi = *(const float2*)(e5s + (size_t)i0 * 8 + 4);
    const int i1x = beg + 4 + g;
    const int i1 = (i1x < end) ? i1x : beg;
    float4 e1lo = *(const float4*)(e5s + (size_t)i1 * 8);
    float2 e1hi = *(const float2*)(e5s + (size_t)i1 * 8 + 4);
    const int i2x = beg + 8 + g;
    const int i2 = (i2x < end) ? i2x : beg;
    float4 e2lo = *(const float4*)(e5s + (size_t)i2 * 8);
    float2 e2hi = *(const float2*)(e5s + (size_t)i2 * 8 + 4);
    const float* kp0 = (const float*)(kvc + (size_t)(unsigned)__float_as_int(e0hi.y)) + t * 4;
    float4 k40 = *(const float4*)(kp0);
    float4 v40 = *(const float4*)(kp0 + 64);
    const float* kp1 = (const float*)(kvc + (size_t)(unsigned)__float_as_int(e1hi.y)) + t * 4;
    float4 k41 = *(const float4*)(kp1);
    float4 v41 = *(const float4*)(kp1 + 64);
    for (int p = beg; p < end; p += 4) {
        // e5 prefetch for iter p+12
        const int nx = p + 12 + g;
        const int npp = (nx < end) ? nx : beg;
        const float4 nlo = *(const float4*)(e5s + (size_t)npp * 8);
        const float2 nhi = *(const float2*)(e5s + (size_t)npp * 8 + 4);
        // kv gather for iter p+8 (e2 loaded 2 iters ago -> src resident)
        const float* kpn =
            (const float*)(kvc + (size_t)(unsigned)__float_as_int(e2hi.y)) + t * 4;
        const float4 nk4 = *(const float4*)(kpn);
        const float4 nv4 = *(const float4*)(kpn + 64);
        // compute current edge (k40/v40 gathered 2 iters ago)
        const bool act = (p + g) < end;
        float d = q4.x * k40.x;
        d = fmaf(q4.y, k40.y, d);
        d = fmaf(q4.z, k40.z, d);
        d = fmaf(q4.w, k40.w, d);
        d += __shfl_xor(d, 1);
        d += __shfl_xor(d, 2);
        d += __shfl_xor(d, 4);
        d += __shfl_xor(d, 8);
        float d5 = g5[0] * e0lo.x;
        d5 = fmaf(g5[1], e0lo.y, d5);
        d5 = fmaf(g5[2], e0lo.z, d5);
        d5 = fmaf(g5[3], e0lo.w, d5);
        d5 = fmaf(g5[4], e0hi.x, d5);
        const float la = act ? (d + d5) : -1e30f;
        const float nm = fmaxf(m, la);
        const float scl = __expf(m - nm);
        const float pa = __expf(la - nm);
        l = fmaf(l, scl, pa);
        accv.x = fmaf(accv.x, scl, pa * v40.x);
        accv.y = fmaf(accv.y, scl, pa * v40.y);
        accv.z = fmaf(accv.z, scl, pa * v40.z);
        accv.w = fmaf(accv.w, scl, pa * v40.w);
        a50 = fmaf(a50, scl, pa * e0lo.x);
        a51 = fmaf(a51, scl, pa * e0lo.y);
        a52 = fmaf(a52, scl, pa * e0lo.z);
        a53 = fmaf(a53, scl, pa * e0lo.w);
        a54 = fmaf(a54, scl, pa * e0hi.x);
        m = nm;
        // rotate pipeline
        e0lo = e1lo; e0hi = e1hi;
        e1lo = e2lo; e1hi = e2hi;
        e2lo = nlo;  e2hi = nhi;
        k40 = k41;   v40 = v41;
        k41 = nk4;   v41 = nv4;
    }
    // ---- merge the 4 per-group states (flash-style) ----
    float M = fmaxf(m, __shfl_xor(m, 16));
    M = fmaxf(M, __shfl_xor(M, 32));
    const float f = __expf(m - M);  // 0 for never-active groups
    float lz = l * f;
    lz += __shfl_xor(lz, 16);
    lz += __shfl_xor(lz, 32);
    accv.x *= f;
    accv.y *= f;
    accv.z *= f;
    accv.w *= f;
    a50 *= f;
    a51 *= f;
    a52 *= f;
    a53 *= f;
    a54 *= f;
#pragma unroll
    for (int s = 16; s <= 32; s <<= 1) {
        accv.x += __shfl_xor(accv.x, s);
        accv.y += __shfl_xor(accv.y, s);
        accv.z += __shfl_xor(accv.z, s);
        accv.w += __shfl_xor(accv.w, s);
        a50 += __shfl_xor(a50, s);
        a51 += __shfl_xor(a51, s);
        a52 += __shfl_xor(a52, s);
        a53 += __shfl_xor(a53, s);
        a54 += __shfl_xor(a54, s);
    }
    // fold edge-feature accumulator back through wE; add skip
    float4 t4 = accv;
    {
        const float4 w0 = *(const float4*)(wE + 0 * 64 + t * 4);
        const float4 w1 = *(const float4*)(wE + 1 * 64 + t * 4);
        const float4 w2 = *(const float4*)(wE + 2 * 64 + t * 4);
        const float4 w3 = *(const float4*)(wE + 3 * 64 + t * 4);
        const float4 w4r = *(const float4*)(wE + 4 * 64 + t * 4);
        t4.x = fmaf(a50, w0.x, t4.x);
        t4.y = fmaf(a50, w0.y, t4.y);
        t4.z = fmaf(a50, w0.z, t4.z);
        t4.w = fmaf(a50, w0.w, t4.w);
        t4.x = fmaf(a51, w1.x, t4.x);
        t4.y = fmaf(a51, w1.y, t4.y);
        t4.z = fmaf(a51, w1.z, t4.z);
        t4.w = fmaf(a51, w1.w, t4.w);
        t4.x = fmaf(a52, w2.x, t4.x);
        t4.y = fmaf(a52, w2.y, t4.y);
        t4.z = fmaf(a52, w2.z, t4.z);
        t4.w = fmaf(a52, w2.w, t4.w);
        t4.x = fmaf(a53, w3.x, t4.x);
        t4.y = fmaf(a53, w3.y, t4.y);
        t4.z = fmaf(a53, w3.z, t4.z);
        t4.w = fmaf(a53, w3.w, t4.w);
        t4.x = fmaf(a54, w4r.x, t4.x);
        t4.y = fmaf(a54, w4r.y, t4.y);
        t4.z = fmaf(a54, w4r.z, t4.z);
        t4.w = fmaf(a54, w4r.w, t4.w);
    }
    const float4 s4 = *(const float4*)(sk + (size_t)node * 64 + t * 4);
    const float rl = 1.f / lz;
    float4 o;
    o.x = fmaf(t4.x, rl, s4.x);
    o.y = fmaf(t4.y, rl, s4.y);
    o.z = fmaf(t4.z, rl, s4.z);
    o.w = fmaf(t4.w, rl, s4.w);
    if (FINAL) {
        const float4 lw4 = *(const float4*)(lw + t * 4);
        float r = o.x * lw4.x;
        r = fmaf(o.y, lw4.y, r);
        r = fmaf(o.z, lw4.z, r);
        r = fmaf(o.w, lw4.w, r);
        r += __shfl_xor(r, 1);
        r += __shfl_xor(r, 2);
        r += __shfl_xor(r, 4);
        r += __shfl_xor(r, 8);
        if (lane == 0) hout[node] = r + lb[0];
    } else if (g == 0) {
        *(float4*)(hout + (size_t)node * 64 + t * 4) = o;
    }
}

extern "C" void kernel_launch(void* const* d_in, const int* in_sizes, int n_in,
                              void* d_out, int out_size, void* d_ws, size_t ws_size,
                              hipStream_t stream) {
    const float* x = (const float*)d_in[0];
    const int* ei = (const int*)d_in[1];
    const float* ea = (const float*)d_in[2];
    const float* w1q = (const float*)d_in[3];
    const float* b1q = (const float*)d_in[4];
    const float* w1k = (const float*)d_in[5];
    const float* b1k = (const float*)d_in[6];
    const float* w1v = (const float*)d_in[7];
    const float* b1v = (const float*)d_in[8];
    const float* w1e = (const float*)d_in[9];
    const float* w1s = (const float*)d_in[10];
    const float* b1s = (const float*)d_in[11];
    const float* wq = (const float*)d_in[12];
    const float* bq = (const float*)d_in[13];
    const float* wk = (const float*)d_in[14];
    const float* bk = (const float*)d_in[15];
    const float* wv = (const float*)d_in[16];
    const float* bv = (const float*)d_in[17];
    const float* we = (const float*)d_in[18];
    const float* ws = (const float*)d_in[19];
    const float* bs = (const float*)d_in[20];
    const float* lw = (const float*)d_in[21];
    const float* lb = (const float*)d_in[22];

    // ---- workspace carve (256B aligned), ~90 MB ----
    uintptr_t p = (uintptr_t)d_ws;
    auto alloc = [&](size_t bytes) -> void* {
        void* r = (void*)p;
        p += (bytes + 255) & ~(size_t)255;
        return r;
    };
    float* e5s = (float*)alloc((size_t)NE * 8 * 4);    // 25.6 MB, dst-sorted rows
    float* hb = (float*)alloc((size_t)NN * HD * 4);    // 12.8 MB
    float* kvb = (float*)alloc((size_t)NN * 128 * 4);  // 25.6 MB interleaved k|v
    float* qb = (float*)alloc((size_t)NN * HD * 4);
    float* sb = (float*)alloc((size_t)NN * HD * 4);
    int* row_start = (int*)alloc((size_t)(NN + 1) * 4);
    int* cnt = (int*)alloc((size_t)NN * 4);
    int* cur = (int*)alloc((size_t)NN * 4);
    int* bsum = (int*)alloc((size_t)SB * 4);
    int* boff = (int*)alloc((size_t)SB * 4);

    // ---- preprocess (once per call) ----
    hipMemsetAsync(cnt, 0, (size_t)NN * 4, stream);
    k_hist<<<(NE + 255) / 256, 256, 0, stream>>>(ei, cnt);
    k_scan1<<<SB, 256, 0, stream>>>(cnt, row_start, bsum);
    k_scan2<<<1, 64, 0, stream>>>(bsum, boff, row_start);
    k_scan3<<<SB, 256, 0, stream>>>(row_start, boff, cur);
    k_scatter<<<(NE + 255) / 256, 256, 0, stream>>>(ei, ea, cur, e5s);

    const int gg64 = 2048;              // fused GEMM grid (8 blocks/CU)
    const int gg10 = (NN + 63) / 64;    // 782
    const int agg_grid = (NN + 3) / 4;  // 12500

    // ---- layer 1 (DIN=10, log1p fused) ----
    k_qkvs10<<<gg10, 256, 0, stream>>>(x, w1q, b1q, w1k, b1k, w1v, b1v, w1s, b1s,
                                       qb, kvb, sb);
    k_agg<false><<<agg_grid, 256, 0, stream>>>(qb, kvb, sb, e5s, w1e, row_start, hb,
                                               lw, lb);

    // ---- layers 2..6 (DIN=64); last layer fuses the output linear ----
    for (int i = 0; i < 5; ++i) {
        k_qkvs64<<<gg64, 256, 0, stream>>>(hb, wq + i * 4096, bq + i * 64,
                                           wk + i * 4096, bk + i * 64,
                                           wv + i * 4096, bv + i * 64,
                                           ws + i * 4096, bs + i * 64,
                                           qb, kvb, sb);
        if (i < 4) {
            k_agg<false><<<agg_grid, 256, 0, stream>>>(qb, kvb, sb, e5s, we + i * 320,
                                                       row_start, hb, lw, lb);
        } else {
            k_agg<true><<<agg_grid, 256, 0, stream>>>(qb, kvb, sb, e5s, we + i * 320,
                                                      row_start, (float*)d_out, lw, lb);
        }
    }
}

// Round 10
// 742.339 us; speedup vs baseline: 1.0995x; 1.0160x over previous
//
#include <hip/hip_runtime.h>
#include <cstdint>
#include <cstddef>

#define NN 50000
#define NE 800000
#define HD 64
#define SB 49  // scan blocks = ceil(50000/1024)

// ---------------- CSR build: histogram ----------------
__global__ void k_hist(const int* __restrict__ ei, int* __restrict__ cnt) {
    int e = blockIdx.x * blockDim.x + threadIdx.x;
    if (e < NE) atomicAdd(&cnt[ei[NE + e]], 1);
}

// ------- hierarchical scan, phase 1: per-block local exclusive scan -------
__global__ __launch_bounds__(256) void k_scan1(const int* __restrict__ cnt,
                                               int* __restrict__ row_start,
                                               int* __restrict__ bsum) {
    __shared__ int ssum[256];
    const int tid = threadIdx.x, b = blockIdx.x;
    const int i0 = b * 1024 + tid * 4;
    int c0 = 0, c1 = 0, c2 = 0, c3 = 0;
    if (i0 + 3 < NN) {
        const int4 c = *(const int4*)(cnt + i0);
        c0 = c.x; c1 = c.y; c2 = c.z; c3 = c.w;
    } else {
        if (i0 + 0 < NN) c0 = cnt[i0 + 0];
        if (i0 + 1 < NN) c1 = cnt[i0 + 1];
        if (i0 + 2 < NN) c2 = cnt[i0 + 2];
        if (i0 + 3 < NN) c3 = cnt[i0 + 3];
    }
    ssum[tid] = c0 + c1 + c2 + c3;
    __syncthreads();
    for (int off = 1; off < 256; off <<= 1) {
        int v = (tid >= off) ? ssum[tid - off] : 0;
        __syncthreads();
        ssum[tid] += v;
        __syncthreads();
    }
    int ex = (tid == 0) ? 0 : ssum[tid - 1];
    if (i0 + 0 < NN) row_start[i0 + 0] = ex;
    ex += c0;
    if (i0 + 1 < NN) row_start[i0 + 1] = ex;
    ex += c1;
    if (i0 + 2 < NN) row_start[i0 + 2] = ex;
    ex += c2;
    if (i0 + 3 < NN) row_start[i0 + 3] = ex;
    if (tid == 255) bsum[b] = ssum[255];
}

// ------- scan phase 2: scan the 49 block sums -------
__global__ __launch_bounds__(64) void k_scan2(const int* __restrict__ bsum,
                                              int* __restrict__ boff,
                                              int* __restrict__ row_start) {
    __shared__ int s[64];
    const int t = threadIdx.x;
    s[t] = (t < SB) ? bsum[t] : 0;
    __syncthreads();
    for (int off = 1; off < 64; off <<= 1) {
        int v = (t >= off) ? s[t - off] : 0;
        __syncthreads();
        s[t] += v;
        __syncthreads();
    }
    if (t < SB) boff[t] = (t == 0) ? 0 : s[t - 1];
    if (t == 0) row_start[NN] = s[SB - 1];  // = NE
}

// ------- scan phase 3: add block offsets; init cur = row_start -------
__global__ __launch_bounds__(256) void k_scan3(int* __restrict__ row_start,
                                               const int* __restrict__ boff,
                                               int* __restrict__ cur) {
    const int b = blockIdx.x;
    const int i0 = b * 1024 + threadIdx.x * 4;
    const int o = boff[b];
#pragma unroll
    for (int k = 0; k < 4; ++k) {
        int i = i0 + k;
        if (i < NN) {
            int v = row_start[i] + o;
            row_start[i] = v;
            cur[i] = v;
        }
    }
}

// ------- CSR scatter: row = [e0..e3, e4, src_byteoff, 0, 0] dst-sorted -------
__global__ void k_scatter(const int* __restrict__ ei, const float* __restrict__ ea,
                          int* __restrict__ cur, float* __restrict__ e5s) {
    int e = blockIdx.x * blockDim.x + threadIdx.x;
    if (e < NE) {
        int d = ei[NE + e];
        int pos = atomicAdd(&cur[d], 1);
        float4 lo;
        lo.x = __logf(ea[e * 5 + 0] + 1.f);
        lo.y = __logf(ea[e * 5 + 1] + 1.f);
        lo.z = __logf(ea[e * 5 + 2] + 1.f);
        lo.w = __logf(ea[e * 5 + 3] + 1.f);
        float4 hi;
        hi.x = __logf(ea[e * 5 + 4] + 1.f);
        hi.y = __int_as_float(ei[e] << 9);  // byte offset into kv (src*512)
        hi.z = 0.f;
        hi.w = 0.f;
        *(float4*)(e5s + (size_t)pos * 8) = lo;
        *(float4*)(e5s + (size_t)pos * 8 + 4) = hi;
    }
}

// ------- fused 4-matrix GEMM, DIN=64: 2-matrix waves, pipelined staging -------
// Block = 4 waves = 2 wave-pairs; pair p handles quad (blockIdx*2+p); within a
// pair, half=0 computes q+k, half=1 computes v+s (two 64-VGPR weight sets), so
// each broadcast ds_read_b128 feeds 8 FMAs (2x fewer LDS reads than 1-matrix
// waves). Each wave stages its own tile copy (wave-synchronous, no barriers);
// the next quad's global load is issued before compute so vmcnt waits on a
// ~700-cycle-old load.
__global__ __launch_bounds__(256) void k_qkvs64(
    const float* __restrict__ h,
    const float* __restrict__ Wq, const float* __restrict__ Bq,
    const float* __restrict__ Wk, const float* __restrict__ Bk,
    const float* __restrict__ Wv, const float* __restrict__ Bv,
    const float* __restrict__ Ws, const float* __restrict__ Bs,
    float* __restrict__ qb, float* __restrict__ kvb, float* __restrict__ sb) {
    __shared__ float xs[4][256];
    const int lane = threadIdx.x & 63;
    const int w = threadIdx.x >> 6;
    const int pair = w >> 1, half = w & 1;
    const float* W0 = half ? Wv : Wq;
    const float* B0 = half ? Bv : Bq;
    const float* W1 = half ? Ws : Wk;
    const float* B1 = half ? Bs : Bk;
    float* O0 = half ? (kvb + 64) : qb;
    float* O1 = half ? sb : kvb;
    const int ldo0 = half ? 128 : 64;
    const int ldo1 = half ? 64 : 128;
    float w0[64], w1[64];
#pragma unroll
    for (int j = 0; j < 64; ++j) {
        w0[j] = W0[j * 64 + lane];
        w1[j] = W1[j * 64 + lane];
    }
    const float b0 = B0[lane], b1 = B1[lane];
    const int nquad = NN / 4;  // 12500
    const int step = gridDim.x * 2;
    int quad = blockIdx.x * 2 + pair;
    if (quad >= nquad) return;
    // preamble: stage quad 0
    {
        const float4 g = *(const float4*)(h + (size_t)quad * 256 + lane * 4);
        *(float4*)&xs[w][lane * 4] = g;
    }
    while (true) {
        const int nq = quad + step;
        const bool more = nq < nquad;
        float4 gn;
        if (more) gn = *(const float4*)(h + (size_t)nq * 256 + lane * 4);  // in flight
        float a0[4] = {b0, b0, b0, b0};
        float a1[4] = {b1, b1, b1, b1};
#pragma unroll
        for (int jq = 0; jq < 16; ++jq) {
#pragma unroll
            for (int n = 0; n < 4; ++n) {
                const float4 xv = *(const float4*)&xs[w][n * 64 + jq * 4];  // broadcast
                a0[n] = fmaf(xv.x, w0[jq * 4 + 0], a0[n]);
                a1[n] = fmaf(xv.x, w1[jq * 4 + 0], a1[n]);
                a0[n] = fmaf(xv.y, w0[jq * 4 + 1], a0[n]);
                a1[n] = fmaf(xv.y, w1[jq * 4 + 1], a1[n]);
                a0[n] = fmaf(xv.z, w0[jq * 4 + 2], a0[n]);
                a1[n] = fmaf(xv.z, w1[jq * 4 + 2], a1[n]);
                a0[n] = fmaf(xv.w, w0[jq * 4 + 3], a0[n]);
                a1[n] = fmaf(xv.w, w1[jq * 4 + 3], a1[n]);
            }
        }
#pragma unroll
        for (int n = 0; n < 4; ++n) {
            O0[(size_t)(quad * 4 + n) * ldo0 + lane] = a0[n];
            O1[(size_t)(quad * 4 + n) * ldo1 + lane] = a1[n];
        }
        if (!more) break;
        *(float4*)&xs[w][lane * 4] = gn;  // after all reads of current tile
        quad = nq;
    }
}

// ------- fused 4-matrix GEMM, DIN=10 (layer 1, log1p fused at staging) -------
__global__ __launch_bounds__(256, 4) void k_qkvs10(
    const float* __restrict__ x,
    const float* __restrict__ Wq, const float* __restrict__ Bq,
    const float* __restrict__ Wk, const float* __restrict__ Bk,
    const float* __restrict__ Wv, const float* __restrict__ Bv,
    const float* __restrict__ Ws, const float* __restrict__ Bs,
    float* __restrict__ qb, float* __restrict__ kvb, float* __restrict__ sb) {
    __shared__ float xs[640];
    const int lane = threadIdx.x & 63;
    const int w = threadIdx.x >> 6;
    const float* W = (w == 0) ? Wq : (w == 1) ? Wk : (w == 2) ? Wv : Ws;
    const float* B = (w == 0) ? Bq : (w == 1) ? Bk : (w == 2) ? Bv : Bs;
    float* outp = (w == 0) ? qb : (w == 1) ? kvb : (w == 2) ? (kvb + 64) : sb;
    const int ldo = (w == 1 || w == 2) ? 128 : 64;
    float wr[10];
#pragma unroll
    for (int j = 0; j < 10; ++j) wr[j] = W[j * 64 + lane];
    const float bias = B[lane];
    const int tile = blockIdx.x;
    const int fbase = tile * 640;
    const int fcnt = min(640, NN * 10 - fbase);
    if (threadIdx.x * 4 < fcnt) {
        float4 v = *(const float4*)(x + (size_t)fbase + threadIdx.x * 4);
        v.x = __logf(v.x + 1.f);
        v.y = __logf(v.y + 1.f);
        v.z = __logf(v.z + 1.f);
        v.w = __logf(v.w + 1.f);
        *(float4*)&xs[threadIdx.x * 4] = v;
    }
    __syncthreads();
    const int nbase = tile * 64;
    const int nodes = min(64, NN - nbase);
    for (int n = 0; n < nodes; ++n) {
        float acc = bias;
#pragma unroll
        for (int j = 0; j < 10; ++j) acc = fmaf(xs[n * 10 + j], wr[j], acc);
        outp[(size_t)(nbase + n) * ldo + lane] = acc;
    }
}

// ---------------- per-dst-node online-softmax aggregation ----------------
// R6 structure (depth-1 pipeline, 32 VGPR, high occupancy): one wave per dst
// node; 4 edges/iter; g = lane>>4 (edge slot), t = lane&15. Per-group softmax
// state + flash merge; 2 exps/iter. #pragma unroll 2 lets the compiler rename
// away the pipeline-rotation movs. FINAL folds the output linear.
template <bool FINAL>
__global__ __launch_bounds__(256) void k_agg(
    const float* __restrict__ q, const float* __restrict__ kv,
    const float* __restrict__ sk, const float* __restrict__ e5s,
    const float* __restrict__ wE, const int* __restrict__ row_start,
    float* __restrict__ hout, const float* __restrict__ lw, const float* lb) {
    const int lane = threadIdx.x & 63;
    const int g = lane >> 4, t = lane & 15;
    const int node = __builtin_amdgcn_readfirstlane(blockIdx.x * 4 + (threadIdx.x >> 6));
    if (node >= NN) return;
    const int beg = row_start[node], end = row_start[node + 1];
    if (beg == end) {
        const float4 s4 = *(const float4*)(sk + (size_t)node * 64 + t * 4);
        if (FINAL) {
            const float4 lw4 = *(const float4*)(lw + t * 4);
            float r = s4.x * lw4.x;
            r = fmaf(s4.y, lw4.y, r);
            r = fmaf(s4.z, lw4.z, r);
            r = fmaf(s4.w, lw4.w, r);
            r += __shfl_xor(r, 1);
            r += __shfl_xor(r, 2);
            r += __shfl_xor(r, 4);
            r += __shfl_xor(r, 8);
            if (lane == 0) hout[node] = r + lb[0];
        } else if (g == 0) {
            *(float4*)(hout + (size_t)node * 64 + t * 4) = s4;
        }
        return;
    }
    float4 q4 = *(const float4*)(q + (size_t)node * 64 + t * 4);
    q4.x *= 0.125f;
    q4.y *= 0.125f;
    q4.z *= 0.125f;
    q4.w *= 0.125f;
    // g5[c] = dot64(q*0.125, wE row c) via in-group butterfly
    float g5[5];
#pragma unroll
    for (int c = 0; c < 5; ++c) {
        const float4 w4 = *(const float4*)(wE + c * 64 + t * 4);
        float d = q4.x * w4.x;
        d = fmaf(q4.y, w4.y, d);
        d = fmaf(q4.z, w4.z, d);
        d = fmaf(q4.w, w4.w, d);
        d += __shfl_xor(d, 1);
        d += __shfl_xor(d, 2);
        d += __shfl_xor(d, 4);
        d += __shfl_xor(d, 8);
        g5[c] = d;
    }
    // per-group online-softmax state
    float m = -1e30f, l = 0.f;
    float4 accv = {0.f, 0.f, 0.f, 0.f};
    float a50 = 0.f, a51 = 0.f, a52 = 0.f, a53 = 0.f, a54 = 0.f;
    const char* kvc = (const char*)kv;
    // pipeline preamble: e5 2-deep, kv 1-deep
    const int i0x = beg + g;
    const int i0 = (i0x < end) ? i0x : beg;
    float4 e0lo = *(const float4*)(e5s + (size_t)i0 * 8);
    float2 e0hi = *(const float2*)(e5s + (size_t)i0 * 8 + 4);
    const int i1x = beg + 4 + g;
    const int i1 = (i1x < end) ? i1x : beg;
    float4 e1lo = *(const float4*)(e5s + (size_t)i1 * 8);
    float2 e1hi = *(const float2*)(e5s + (size_t)i1 * 8 + 4);
    const float* kp0 = (const float*)(kvc + (size_t)(unsigned)__float_as_int(e0hi.y)) + t * 4;
    float4 k4 = *(const float4*)(kp0);
    float4 v4 = *(const float4*)(kp0 + 64);
#pragma unroll 2
    for (int p = beg; p < end; p += 4) {
        // e5 prefetch for iter p+8 (sequential, L2-friendly)
        const int nx = p + 8 + g;
        const int npp = (nx < end) ? nx : beg;
        const float4 nlo = *(const float4*)(e5s + (size_t)npp * 8);
        const float2 nhi = *(const float2*)(e5s + (size_t)npp * 8 + 4);
        // kv gather for iter p+4 (e1 landed one iter ago)
        const float* kpn =
            (const float*)(kvc + (size_t)(unsigned)__float_as_int(e1hi.y)) + t * 4;
        const float4 nk4 = *(const float4*)(kpn);
        const float4 nv4 = *(const float4*)(kpn + 64);
        // compute current edge
        const bool act = (p + g) < end;
        float d = q4.x * k4.x;
        d = fmaf(q4.y, k4.y, d);
        d = fmaf(q4.z, k4.z, d);
        d = fmaf(q4.w, k4.w, d);
        d += __shfl_xor(d, 1);
        d += __shfl_xor(d, 2);
        d += __shfl_xor(d, 4);
        d += __shfl_xor(d, 8);
        float d5 = g5[0] * e0lo.x;
        d5 = fmaf(g5[1], e0lo.y, d5);
        d5 = fmaf(g5[2], e0lo.z, d5);
        d5 = fmaf(g5[3], e0lo.w, d5);
        d5 = fmaf(g5[4], e0hi.x, d5);
        const float la = act ? (d + d5) : -1e30f;
        const float nm = fmaxf(m, la);
        const float scl = __expf(m - nm);
        const float pa = __expf(la - nm);
        l = fmaf(l, scl, pa);
        accv.x = fmaf(accv.x, scl, pa * v4.x);
        accv.y = fmaf(accv.y, scl, pa * v4.y);
        accv.z = fmaf(accv.z, scl, pa * v4.z);
        accv.w = fmaf(accv.w, scl, pa * v4.w);
        a50 = fmaf(a50, scl, pa * e0lo.x);
        a51 = fmaf(a51, scl, pa * e0lo.y);
        a52 = fmaf(a52, scl, pa * e0lo.z);
        a53 = fmaf(a53, scl, pa * e0lo.w);
        a54 = fmaf(a54, scl, pa * e0hi.x);
        m = nm;
        // rotate pipeline (renamed away by unroll 2)
        e0lo = e1lo;
        e0hi = e1hi;
        e1lo = nlo;
        e1hi = nhi;
        k4 = nk4;
        v4 = nv4;
    }
    // ---- merge the 4 per-group states (flash-style) ----
    float M = fmaxf(m, __shfl_xor(m, 16));
    M = fmaxf(M, __shfl_xor(M, 32));
    const float f = __expf(m - M);  // 0 for never-active groups
    float lz = l * f;
    lz += __shfl_xor(lz, 16);
    lz += __shfl_xor(lz, 32);
    accv.x *= f;
    accv.y *= f;
    accv.z *= f;
    accv.w *= f;
    a50 *= f;
    a51 *= f;
    a52 *= f;
    a53 *= f;
    a54 *= f;
#pragma unroll
    for (int s = 16; s <= 32; s <<= 1) {
        accv.x += __shfl_xor(accv.x, s);
        accv.y += __shfl_xor(accv.y, s);
        accv.z += __shfl_xor(accv.z, s);
        accv.w += __shfl_xor(accv.w, s);
        a50 += __shfl_xor(a50, s);
        a51 += __shfl_xor(a51, s);
        a52 += __shfl_xor(a52, s);
        a53 += __shfl_xor(a53, s);
        a54 += __shfl_xor(a54, s);
    }
    // fold edge-feature accumulator back through wE; add skip
    float4 t4 = accv;
    {
        const float4 w0 = *(const float4*)(wE + 0 * 64 + t * 4);
        const float4 w1 = *(const float4*)(wE + 1 * 64 + t * 4);
        const float4 w2 = *(const float4*)(wE + 2 * 64 + t * 4);
        const float4 w3 = *(const float4*)(wE + 3 * 64 + t * 4);
        const float4 w4r = *(const float4*)(wE + 4 * 64 + t * 4);
        t4.x = fmaf(a50, w0.x, t4.x);
        t4.y = fmaf(a50, w0.y, t4.y);
        t4.z = fmaf(a50, w0.z, t4.z);
        t4.w = fmaf(a50, w0.w, t4.w);
        t4.x = fmaf(a51, w1.x, t4.x);
        t4.y = fmaf(a51, w1.y, t4.y);
        t4.z = fmaf(a51, w1.z, t4.z);
        t4.w = fmaf(a51, w1.w, t4.w);
        t4.x = fmaf(a52, w2.x, t4.x);
        t4.y = fmaf(a52, w2.y, t4.y);
        t4.z = fmaf(a52, w2.z, t4.z);
        t4.w = fmaf(a52, w2.w, t4.w);
        t4.x = fmaf(a53, w3.x, t4.x);
        t4.y = fmaf(a53, w3.y, t4.y);
        t4.z = fmaf(a53, w3.z, t4.z);
        t4.w = fmaf(a53, w3.w, t4.w);
        t4.x = fmaf(a54, w4r.x, t4.x);
        t4.y = fmaf(a54, w4r.y, t4.y);
        t4.z = fmaf(a54, w4r.z, t4.z);
        t4.w = fmaf(a54, w4r.w, t4.w);
    }
    const float4 s4 = *(const float4*)(sk + (size_t)node * 64 + t * 4);
    const float rl = 1.f / lz;
    float4 o;
    o.x = fmaf(t4.x, rl, s4.x);
    o.y = fmaf(t4.y, rl, s4.y);
    o.z = fmaf(t4.z, rl, s4.z);
    o.w = fmaf(t4.w, rl, s4.w);
    if (FINAL) {
        const float4 lw4 = *(const float4*)(lw + t * 4);
        float r = o.x * lw4.x;
        r = fmaf(o.y, lw4.y, r);
        r = fmaf(o.z, lw4.z, r);
        r = fmaf(o.w, lw4.w, r);
        r += __shfl_xor(r, 1);
        r += __shfl_xor(r, 2);
        r += __shfl_xor(r, 4);
        r += __shfl_xor(r, 8);
        if (lane == 0) hout[node] = r + lb[0];
    } else if (g == 0) {
        *(float4*)(hout + (size_t)node * 64 + t * 4) = o;
    }
}

extern "C" void kernel_launch(void* const* d_in, const int* in_sizes, int n_in,
                              void* d_out, int out_size, void* d_ws, size_t ws_size,
                              hipStream_t stream) {
    const float* x = (const float*)d_in[0];
    const int* ei = (const int*)d_in[1];
    const float* ea = (const float*)d_in[2];
    const float* w1q = (const float*)d_in[3];
    const float* b1q = (const float*)d_in[4];
    const float* w1k = (const float*)d_in[5];
    const float* b1k = (const float*)d_in[6];
    const float* w1v = (const float*)d_in[7];
    const float* b1v = (const float*)d_in[8];
    const float* w1e = (const float*)d_in[9];
    const float* w1s = (const float*)d_in[10];
    const float* b1s = (const float*)d_in[11];
    const float* wq = (const float*)d_in[12];
    const float* bq = (const float*)d_in[13];
    const float* wk = (const float*)d_in[14];
    const float* bk = (const float*)d_in[15];
    const float* wv = (const float*)d_in[16];
    const float* bv = (const float*)d_in[17];
    const float* we = (const float*)d_in[18];
    const float* ws = (const float*)d_in[19];
    const float* bs = (const float*)d_in[20];
    const float* lw = (const float*)d_in[21];
    const float* lb = (const float*)d_in[22];

    // ---- workspace carve (256B aligned), ~90 MB ----
    uintptr_t p = (uintptr_t)d_ws;
    auto alloc = [&](size_t bytes) -> void* {
        void* r = (void*)p;
        p += (bytes + 255) & ~(size_t)255;
        return r;
    };
    float* e5s = (float*)alloc((size_t)NE * 8 * 4);    // 25.6 MB, dst-sorted rows
    float* hb = (float*)alloc((size_t)NN * HD * 4);    // 12.8 MB
    float* kvb = (float*)alloc((size_t)NN * 128 * 4);  // 25.6 MB interleaved k|v
    float* qb = (float*)alloc((size_t)NN * HD * 4);
    float* sb = (float*)alloc((size_t)NN * HD * 4);
    int* row_start = (int*)alloc((size_t)(NN + 1) * 4);
    int* cnt = (int*)alloc((size_t)NN * 4);
    int* cur = (int*)alloc((size_t)NN * 4);
    int* bsum = (int*)alloc((size_t)SB * 4);
    int* boff = (int*)alloc((size_t)SB * 4);

    // ---- preprocess (once per call) ----
    hipMemsetAsync(cnt, 0, (size_t)NN * 4, stream);
    k_hist<<<(NE + 255) / 256, 256, 0, stream>>>(ei, cnt);
    k_scan1<<<SB, 256, 0, stream>>>(cnt, row_start, bsum);
    k_scan2<<<1, 64, 0, stream>>>(bsum, boff, row_start);
    k_scan3<<<SB, 256, 0, stream>>>(row_start, boff, cur);
    k_scatter<<<(NE + 255) / 256, 256, 0, stream>>>(ei, ea, cur, e5s);

    const int gg64 = 2048;              // 2 quads/block -> 4096 quads per sweep
    const int gg10 = (NN + 63) / 64;    // 782
    const int agg_grid = (NN + 3) / 4;  // 12500

    // ---- layer 1 (DIN=10, log1p fused) ----
    k_qkvs10<<<gg10, 256, 0, stream>>>(x, w1q, b1q, w1k, b1k, w1v, b1v, w1s, b1s,
                                       qb, kvb, sb);
    k_agg<false><<<agg_grid, 256, 0, stream>>>(qb, kvb, sb, e5s, w1e, row_start, hb,
                                               lw, lb);

    // ---- layers 2..6 (DIN=64); last layer fuses the output linear ----
    for (int i = 0; i < 5; ++i) {
        k_qkvs64<<<gg64, 256, 0, stream>>>(hb, wq + i * 4096, bq + i * 64,
                                           wk + i * 4096, bk + i * 64,
                                           wv + i * 4096, bv + i * 64,
                                           ws + i * 4096, bs + i * 64,
                                           qb, kvb, sb);
        if (i < 4) {
            k_agg<false><<<agg_grid, 256, 0, stream>>>(qb, kvb, sb, e5s, we + i * 320,
                                                       row_start, hb, lw, lb);
        } else {
            k_agg<true><<<agg_grid, 256, 0, stream>>>(qb, kvb, sb, e5s, we + i * 320,
                                                      row_start, (float*)d_out, lw, lb);
        }
    }
}

// Round 11
// 736.925 us; speedup vs baseline: 1.1075x; 1.0073x over previous
//
#include <hip/hip_runtime.h>
#include <cstdint>
#include <cstddef>

#define NN 50000
#define NE 800000
#define HD 64
#define SB 49  // scan blocks = ceil(50000/1024)

// ---------------- CSR build: histogram ----------------
__global__ void k_hist(const int* __restrict__ ei, int* __restrict__ cnt) {
    int e = blockIdx.x * blockDim.x + threadIdx.x;
    if (e < NE) atomicAdd(&cnt[ei[NE + e]], 1);
}

// ------- hierarchical scan, phase 1: per-block local exclusive scan -------
__global__ __launch_bounds__(256) void k_scan1(const int* __restrict__ cnt,
                                               int* __restrict__ row_start,
                                               int* __restrict__ bsum) {
    __shared__ int ssum[256];
    const int tid = threadIdx.x, b = blockIdx.x;
    const int i0 = b * 1024 + tid * 4;
    int c0 = 0, c1 = 0, c2 = 0, c3 = 0;
    if (i0 + 3 < NN) {
        const int4 c = *(const int4*)(cnt + i0);
        c0 = c.x; c1 = c.y; c2 = c.z; c3 = c.w;
    } else {
        if (i0 + 0 < NN) c0 = cnt[i0 + 0];
        if (i0 + 1 < NN) c1 = cnt[i0 + 1];
        if (i0 + 2 < NN) c2 = cnt[i0 + 2];
        if (i0 + 3 < NN) c3 = cnt[i0 + 3];
    }
    ssum[tid] = c0 + c1 + c2 + c3;
    __syncthreads();
    for (int off = 1; off < 256; off <<= 1) {
        int v = (tid >= off) ? ssum[tid - off] : 0;
        __syncthreads();
        ssum[tid] += v;
        __syncthreads();
    }
    int ex = (tid == 0) ? 0 : ssum[tid - 1];
    if (i0 + 0 < NN) row_start[i0 + 0] = ex;
    ex += c0;
    if (i0 + 1 < NN) row_start[i0 + 1] = ex;
    ex += c1;
    if (i0 + 2 < NN) row_start[i0 + 2] = ex;
    ex += c2;
    if (i0 + 3 < NN) row_start[i0 + 3] = ex;
    if (tid == 255) bsum[b] = ssum[255];
}

// ------- scan phase 2: scan the 49 block sums -------
__global__ __launch_bounds__(64) void k_scan2(const int* __restrict__ bsum,
                                              int* __restrict__ boff,
                                              int* __restrict__ row_start) {
    __shared__ int s[64];
    const int t = threadIdx.x;
    s[t] = (t < SB) ? bsum[t] : 0;
    __syncthreads();
    for (int off = 1; off < 64; off <<= 1) {
        int v = (t >= off) ? s[t - off] : 0;
        __syncthreads();
        s[t] += v;
        __syncthreads();
    }
    if (t < SB) boff[t] = (t == 0) ? 0 : s[t - 1];
    if (t == 0) row_start[NN] = s[SB - 1];  // = NE
}

// ------- scan phase 3: add block offsets; init cur = row_start -------
__global__ __launch_bounds__(256) void k_scan3(int* __restrict__ row_start,
                                               const int* __restrict__ boff,
                                               int* __restrict__ cur) {
    const int b = blockIdx.x;
    const int i0 = b * 1024 + threadIdx.x * 4;
    const int o = boff[b];
#pragma unroll
    for (int k = 0; k < 4; ++k) {
        int i = i0 + k;
        if (i < NN) {
            int v = row_start[i] + o;
            row_start[i] = v;
            cur[i] = v;
        }
    }
}

// ------- CSR scatter: row = [e0..e3, e4, src_byteoff, 0, 0] dst-sorted -------
__global__ void k_scatter(const int* __restrict__ ei, const float* __restrict__ ea,
                          int* __restrict__ cur, float* __restrict__ e5s) {
    int e = blockIdx.x * blockDim.x + threadIdx.x;
    if (e < NE) {
        int d = ei[NE + e];
        int pos = atomicAdd(&cur[d], 1);
        float4 lo;
        lo.x = __logf(ea[e * 5 + 0] + 1.f);
        lo.y = __logf(ea[e * 5 + 1] + 1.f);
        lo.z = __logf(ea[e * 5 + 2] + 1.f);
        lo.w = __logf(ea[e * 5 + 3] + 1.f);
        float4 hi;
        hi.x = __logf(ea[e * 5 + 4] + 1.f);
        hi.y = __int_as_float(ei[e] << 9);  // byte offset into kv (src*512)
        hi.z = 0.f;
        hi.w = 0.f;
        *(float4*)(e5s + (size_t)pos * 8) = lo;
        *(float4*)(e5s + (size_t)pos * 8 + 4) = hi;
    }
}

// ------- fused 4-matrix GEMM, DIN=64: 2-matrix waves, pipelined staging -------
// Grid 768 (3 blocks/CU): each wave loads its 32 KB weight set ONCE and
// amortizes it over ~8 quads (grid 2048 re-fetched weights 8192x = 268 MB).
// Block = 2 wave-pairs; half=0 computes q+k, half=1 v+s; each broadcast
// ds_read_b128 feeds 8 FMAs; wave-private LDS tile, no barriers; next quad's
// global load issued before compute.
__global__ __launch_bounds__(256) void k_qkvs64(
    const float* __restrict__ h,
    const float* __restrict__ Wq, const float* __restrict__ Bq,
    const float* __restrict__ Wk, const float* __restrict__ Bk,
    const float* __restrict__ Wv, const float* __restrict__ Bv,
    const float* __restrict__ Ws, const float* __restrict__ Bs,
    float* __restrict__ qb, float* __restrict__ kvb, float* __restrict__ sb) {
    __shared__ float xs[4][256];
    const int lane = threadIdx.x & 63;
    const int w = threadIdx.x >> 6;
    const int pair = w >> 1, half = w & 1;
    const float* W0 = half ? Wv : Wq;
    const float* B0 = half ? Bv : Bq;
    const float* W1 = half ? Ws : Wk;
    const float* B1 = half ? Bs : Bk;
    float* O0 = half ? (kvb + 64) : qb;
    float* O1 = half ? sb : kvb;
    const int ldo0 = half ? 128 : 64;
    const int ldo1 = half ? 64 : 128;
    float w0[64], w1[64];
#pragma unroll
    for (int j = 0; j < 64; ++j) {
        w0[j] = W0[j * 64 + lane];
        w1[j] = W1[j * 64 + lane];
    }
    const float b0 = B0[lane], b1 = B1[lane];
    const int nquad = NN / 4;  // 12500
    const int step = gridDim.x * 2;
    int quad = blockIdx.x * 2 + pair;
    if (quad >= nquad) return;
    {
        const float4 g = *(const float4*)(h + (size_t)quad * 256 + lane * 4);
        *(float4*)&xs[w][lane * 4] = g;
    }
    while (true) {
        const int nq = quad + step;
        const bool more = nq < nquad;
        float4 gn;
        if (more) gn = *(const float4*)(h + (size_t)nq * 256 + lane * 4);  // in flight
        float a0[4] = {b0, b0, b0, b0};
        float a1[4] = {b1, b1, b1, b1};
#pragma unroll
        for (int jq = 0; jq < 16; ++jq) {
#pragma unroll
            for (int n = 0; n < 4; ++n) {
                const float4 xv = *(const float4*)&xs[w][n * 64 + jq * 4];  // broadcast
                a0[n] = fmaf(xv.x, w0[jq * 4 + 0], a0[n]);
                a1[n] = fmaf(xv.x, w1[jq * 4 + 0], a1[n]);
                a0[n] = fmaf(xv.y, w0[jq * 4 + 1], a0[n]);
                a1[n] = fmaf(xv.y, w1[jq * 4 + 1], a1[n]);
                a0[n] = fmaf(xv.z, w0[jq * 4 + 2], a0[n]);
                a1[n] = fmaf(xv.z, w1[jq * 4 + 2], a1[n]);
                a0[n] = fmaf(xv.w, w0[jq * 4 + 3], a0[n]);
                a1[n] = fmaf(xv.w, w1[jq * 4 + 3], a1[n]);
            }
        }
#pragma unroll
        for (int n = 0; n < 4; ++n) {
            O0[(size_t)(quad * 4 + n) * ldo0 + lane] = a0[n];
            O1[(size_t)(quad * 4 + n) * ldo1 + lane] = a1[n];
        }
        if (!more) break;
        *(float4*)&xs[w][lane * 4] = gn;  // DS ops in-order: after all tile reads
        quad = nq;
    }
}

// ------- fused 4-matrix GEMM, DIN=10 (layer 1, log1p fused at staging) -------
__global__ __launch_bounds__(256, 4) void k_qkvs10(
    const float* __restrict__ x,
    const float* __restrict__ Wq, const float* __restrict__ Bq,
    const float* __restrict__ Wk, const float* __restrict__ Bk,
    const float* __restrict__ Wv, const float* __restrict__ Bv,
    const float* __restrict__ Ws, const float* __restrict__ Bs,
    float* __restrict__ qb, float* __restrict__ kvb, float* __restrict__ sb) {
    __shared__ float xs[640];
    const int lane = threadIdx.x & 63;
    const int w = threadIdx.x >> 6;
    const float* W = (w == 0) ? Wq : (w == 1) ? Wk : (w == 2) ? Wv : Ws;
    const float* B = (w == 0) ? Bq : (w == 1) ? Bk : (w == 2) ? Bv : Bs;
    float* outp = (w == 0) ? qb : (w == 1) ? kvb : (w == 2) ? (kvb + 64) : sb;
    const int ldo = (w == 1 || w == 2) ? 128 : 64;
    float wr[10];
#pragma unroll
    for (int j = 0; j < 10; ++j) wr[j] = W[j * 64 + lane];
    const float bias = B[lane];
    const int tile = blockIdx.x;
    const int fbase = tile * 640;
    const int fcnt = min(640, NN * 10 - fbase);
    if (threadIdx.x * 4 < fcnt) {
        float4 v = *(const float4*)(x + (size_t)fbase + threadIdx.x * 4);
        v.x = __logf(v.x + 1.f);
        v.y = __logf(v.y + 1.f);
        v.z = __logf(v.z + 1.f);
        v.w = __logf(v.w + 1.f);
        *(float4*)&xs[threadIdx.x * 4] = v;
    }
    __syncthreads();
    const int nbase = tile * 64;
    const int nodes = min(64, NN - nbase);
    for (int n = 0; n < nodes; ++n) {
        float acc = bias;
#pragma unroll
        for (int j = 0; j < 10; ++j) acc = fmaf(xs[n * 10 + j], wr[j], acc);
        outp[(size_t)(nbase + n) * ldo + lane] = acc;
    }
}

// ---------------- per-dst-node online-softmax aggregation, 8x8 ----------------
// One wave per dst node; 8 edges/iter; g = lane>>3 (edge slot), t = lane&7.
// Lane owns features {t*4..t*4+3} U {32+t*4..32+t*4+3} so every kv load
// instruction covers a dense 128 B chunk per group (1 KB/wave, full lines).
// Per-group flash state -> 3 shfls per 8 edges in the loop; 2 exps/iter.
// 8-way state merge at the end. FINAL folds the output linear.
template <bool FINAL>
__global__ __launch_bounds__(256) void k_agg(
    const float* __restrict__ q, const float* __restrict__ kv,
    const float* __restrict__ sk, const float* __restrict__ e5s,
    const float* __restrict__ wE, const int* __restrict__ row_start,
    float* __restrict__ hout, const float* __restrict__ lw, const float* lb) {
    const int lane = threadIdx.x & 63;
    const int g = lane >> 3, t = lane & 7;
    const int node = __builtin_amdgcn_readfirstlane(blockIdx.x * 4 + (threadIdx.x >> 6));
    if (node >= NN) return;
    const int beg = row_start[node], end = row_start[node + 1];
    const int oA = t * 4, oB = 32 + t * 4;  // feature offsets owned by this lane
    if (beg == end) {
        const float4 sa = *(const float4*)(sk + (size_t)node * 64 + oA);
        const float4 sb4 = *(const float4*)(sk + (size_t)node * 64 + oB);
        if (FINAL) {
            const float4 lwa = *(const float4*)(lw + oA);
            const float4 lwb = *(const float4*)(lw + oB);
            float r = sa.x * lwa.x;
            r = fmaf(sa.y, lwa.y, r);
            r = fmaf(sa.z, lwa.z, r);
            r = fmaf(sa.w, lwa.w, r);
            r = fmaf(sb4.x, lwb.x, r);
            r = fmaf(sb4.y, lwb.y, r);
            r = fmaf(sb4.z, lwb.z, r);
            r = fmaf(sb4.w, lwb.w, r);
            r += __shfl_xor(r, 1);
            r += __shfl_xor(r, 2);
            r += __shfl_xor(r, 4);
            if (lane == 0) hout[node] = r + lb[0];
        } else if (g == 0) {
            *(float4*)(hout + (size_t)node * 64 + oA) = sa;
            *(float4*)(hout + (size_t)node * 64 + oB) = sb4;
        }
        return;
    }
    float4 qa = *(const float4*)(q + (size_t)node * 64 + oA);
    float4 qb4 = *(const float4*)(q + (size_t)node * 64 + oB);
    qa.x *= 0.125f; qa.y *= 0.125f; qa.z *= 0.125f; qa.w *= 0.125f;
    qb4.x *= 0.125f; qb4.y *= 0.125f; qb4.z *= 0.125f; qb4.w *= 0.125f;
    // g5[c] = dot64(q*0.125, wE row c): 8-lane in-group butterfly
    float g5[5];
#pragma unroll
    for (int c = 0; c < 5; ++c) {
        const float4 wa = *(const float4*)(wE + c * 64 + oA);
        const float4 wb = *(const float4*)(wE + c * 64 + oB);
        float d = qa.x * wa.x;
        d = fmaf(qa.y, wa.y, d);
        d = fmaf(qa.z, wa.z, d);
        d = fmaf(qa.w, wa.w, d);
        d = fmaf(qb4.x, wb.x, d);
        d = fmaf(qb4.y, wb.y, d);
        d = fmaf(qb4.z, wb.z, d);
        d = fmaf(qb4.w, wb.w, d);
        d += __shfl_xor(d, 1);
        d += __shfl_xor(d, 2);
        d += __shfl_xor(d, 4);
        g5[c] = d;
    }
    // per-group online-softmax state
    float m = -1e30f, l = 0.f;
    float4 ava = {0.f, 0.f, 0.f, 0.f}, avb = {0.f, 0.f, 0.f, 0.f};
    float a50 = 0.f, a51 = 0.f, a52 = 0.f, a53 = 0.f, a54 = 0.f;
    const char* kvc = (const char*)kv;
    // pipeline preamble: e5 2-deep, kv 1-deep
    const int i0x = beg + g;
    const int i0 = (i0x < end) ? i0x : beg;
    float4 e0lo = *(const float4*)(e5s + (size_t)i0 * 8);
    float2 e0hi = *(const float2*)(e5s + (size_t)i0 * 8 + 4);
    const int i1x = beg + 8 + g;
    const int i1 = (i1x < end) ? i1x : beg;
    float4 e1lo = *(const float4*)(e5s + (size_t)i1 * 8);
    float2 e1hi = *(const float2*)(e5s + (size_t)i1 * 8 + 4);
    const char* kp0 = kvc + (size_t)(unsigned)__float_as_int(e0hi.y);
    float4 ka = *(const float4*)(kp0 + oA * 4);
    float4 kb = *(const float4*)(kp0 + oB * 4);
    float4 va = *(const float4*)(kp0 + 256 + oA * 4);
    float4 vb = *(const float4*)(kp0 + 256 + oB * 4);
    for (int p = beg; p < end; p += 8) {
        // e5 prefetch for iter p+16
        const int nx = p + 16 + g;
        const int npp = (nx < end) ? nx : beg;
        const float4 nlo = *(const float4*)(e5s + (size_t)npp * 8);
        const float2 nhi = *(const float2*)(e5s + (size_t)npp * 8 + 4);
        // kv gather for iter p+8 (e1 landed one iter ago)
        const char* kpn = kvc + (size_t)(unsigned)__float_as_int(e1hi.y);
        const float4 nka = *(const float4*)(kpn + oA * 4);
        const float4 nkb = *(const float4*)(kpn + oB * 4);
        const float4 nva = *(const float4*)(kpn + 256 + oA * 4);
        const float4 nvb = *(const float4*)(kpn + 256 + oB * 4);
        // compute current edge
        const bool act = (p + g) < end;
        float d = qa.x * ka.x;
        d = fmaf(qa.y, ka.y, d);
        d = fmaf(qa.z, ka.z, d);
        d = fmaf(qa.w, ka.w, d);
        d = fmaf(qb4.x, kb.x, d);
        d = fmaf(qb4.y, kb.y, d);
        d = fmaf(qb4.z, kb.z, d);
        d = fmaf(qb4.w, kb.w, d);
        d += __shfl_xor(d, 1);
        d += __shfl_xor(d, 2);
        d += __shfl_xor(d, 4);
        float d5 = g5[0] * e0lo.x;
        d5 = fmaf(g5[1], e0lo.y, d5);
        d5 = fmaf(g5[2], e0lo.z, d5);
        d5 = fmaf(g5[3], e0lo.w, d5);
        d5 = fmaf(g5[4], e0hi.x, d5);
        const float la = act ? (d + d5) : -1e30f;
        const float nm = fmaxf(m, la);
        const float scl = __expf(m - nm);
        const float pa = __expf(la - nm);
        l = fmaf(l, scl, pa);
        ava.x = fmaf(ava.x, scl, pa * va.x);
        ava.y = fmaf(ava.y, scl, pa * va.y);
        ava.z = fmaf(ava.z, scl, pa * va.z);
        ava.w = fmaf(ava.w, scl, pa * va.w);
        avb.x = fmaf(avb.x, scl, pa * vb.x);
        avb.y = fmaf(avb.y, scl, pa * vb.y);
        avb.z = fmaf(avb.z, scl, pa * vb.z);
        avb.w = fmaf(avb.w, scl, pa * vb.w);
        a50 = fmaf(a50, scl, pa * e0lo.x);
        a51 = fmaf(a51, scl, pa * e0lo.y);
        a52 = fmaf(a52, scl, pa * e0lo.z);
        a53 = fmaf(a53, scl, pa * e0lo.w);
        a54 = fmaf(a54, scl, pa * e0hi.x);
        m = nm;
        // rotate pipeline
        e0lo = e1lo;
        e0hi = e1hi;
        e1lo = nlo;
        e1hi = nhi;
        ka = nka;
        kb = nkb;
        va = nva;
        vb = nvb;
    }
    // ---- merge the 8 per-group states (flash-style butterfly) ----
    float M = fmaxf(m, __shfl_xor(m, 8));
    M = fmaxf(M, __shfl_xor(M, 16));
    M = fmaxf(M, __shfl_xor(M, 32));
    const float f = __expf(m - M);  // 0 for never-active groups
    float lz = l * f;
    ava.x *= f; ava.y *= f; ava.z *= f; ava.w *= f;
    avb.x *= f; avb.y *= f; avb.z *= f; avb.w *= f;
    a50 *= f; a51 *= f; a52 *= f; a53 *= f; a54 *= f;
#pragma unroll
    for (int s = 8; s <= 32; s <<= 1) {
        lz += __shfl_xor(lz, s);
        ava.x += __shfl_xor(ava.x, s);
        ava.y += __shfl_xor(ava.y, s);
        ava.z += __shfl_xor(ava.z, s);
        ava.w += __shfl_xor(ava.w, s);
        avb.x += __shfl_xor(avb.x, s);
        avb.y += __shfl_xor(avb.y, s);
        avb.z += __shfl_xor(avb.z, s);
        avb.w += __shfl_xor(avb.w, s);
        a50 += __shfl_xor(a50, s);
        a51 += __shfl_xor(a51, s);
        a52 += __shfl_xor(a52, s);
        a53 += __shfl_xor(a53, s);
        a54 += __shfl_xor(a54, s);
    }
    // fold edge-feature accumulator back through wE; add skip
    float4 ta = ava, tb = avb;
#pragma unroll
    for (int c = 0; c < 5; ++c) {
        const float ac = (c == 0) ? a50 : (c == 1) ? a51 : (c == 2) ? a52 : (c == 3) ? a53 : a54;
        const float4 wa = *(const float4*)(wE + c * 64 + oA);
        const float4 wb = *(const float4*)(wE + c * 64 + oB);
        ta.x = fmaf(ac, wa.x, ta.x);
        ta.y = fmaf(ac, wa.y, ta.y);
        ta.z = fmaf(ac, wa.z, ta.z);
        ta.w = fmaf(ac, wa.w, ta.w);
        tb.x = fmaf(ac, wb.x, tb.x);
        tb.y = fmaf(ac, wb.y, tb.y);
        tb.z = fmaf(ac, wb.z, tb.z);
        tb.w = fmaf(ac, wb.w, tb.w);
    }
    const float4 sa = *(const float4*)(sk + (size_t)node * 64 + oA);
    const float4 sb4 = *(const float4*)(sk + (size_t)node * 64 + oB);
    const float rl = 1.f / lz;
    float4 oa, ob;
    oa.x = fmaf(ta.x, rl, sa.x);
    oa.y = fmaf(ta.y, rl, sa.y);
    oa.z = fmaf(ta.z, rl, sa.z);
    oa.w = fmaf(ta.w, rl, sa.w);
    ob.x = fmaf(tb.x, rl, sb4.x);
    ob.y = fmaf(tb.y, rl, sb4.y);
    ob.z = fmaf(tb.z, rl, sb4.z);
    ob.w = fmaf(tb.w, rl, sb4.w);
    if (FINAL) {
        const float4 lwa = *(const float4*)(lw + oA);
        const float4 lwb = *(const float4*)(lw + oB);
        float r = oa.x * lwa.x;
        r = fmaf(oa.y, lwa.y, r);
        r = fmaf(oa.z, lwa.z, r);
        r = fmaf(oa.w, lwa.w, r);
        r = fmaf(ob.x, lwb.x, r);
        r = fmaf(ob.y, lwb.y, r);
        r = fmaf(ob.z, lwb.z, r);
        r = fmaf(ob.w, lwb.w, r);
        r += __shfl_xor(r, 1);
        r += __shfl_xor(r, 2);
        r += __shfl_xor(r, 4);
        if (lane == 0) hout[node] = r + lb[0];
    } else if (g == 0) {
        *(float4*)(hout + (size_t)node * 64 + oA) = oa;
        *(float4*)(hout + (size_t)node * 64 + oB) = ob;
    }
}

extern "C" void kernel_launch(void* const* d_in, const int* in_sizes, int n_in,
                              void* d_out, int out_size, void* d_ws, size_t ws_size,
                              hipStream_t stream) {
    const float* x = (const float*)d_in[0];
    const int* ei = (const int*)d_in[1];
    const float* ea = (const float*)d_in[2];
    const float* w1q = (const float*)d_in[3];
    const float* b1q = (const float*)d_in[4];
    const float* w1k = (const float*)d_in[5];
    const float* b1k = (const float*)d_in[6];
    const float* w1v = (const float*)d_in[7];
    const float* b1v = (const float*)d_in[8];
    const float* w1e = (const float*)d_in[9];
    const float* w1s = (const float*)d_in[10];
    const float* b1s = (const float*)d_in[11];
    const float* wq = (const float*)d_in[12];
    const float* bq = (const float*)d_in[13];
    const float* wk = (const float*)d_in[14];
    const float* bk = (const float*)d_in[15];
    const float* wv = (const float*)d_in[16];
    const float* bv = (const float*)d_in[17];
    const float* we = (const float*)d_in[18];
    const float* ws = (const float*)d_in[19];
    const float* bs = (const float*)d_in[20];
    const float* lw = (const float*)d_in[21];
    const float* lb = (const float*)d_in[22];

    // ---- workspace carve (256B aligned), ~90 MB ----
    uintptr_t p = (uintptr_t)d_ws;
    auto alloc = [&](size_t bytes) -> void* {
        void* r = (void*)p;
        p += (bytes + 255) & ~(size_t)255;
        return r;
    };
    float* e5s = (float*)alloc((size_t)NE * 8 * 4);    // 25.6 MB, dst-sorted rows
    float* hb = (float*)alloc((size_t)NN * HD * 4);    // 12.8 MB
    float* kvb = (float*)alloc((size_t)NN * 128 * 4);  // 25.6 MB interleaved k|v
    float* qb = (float*)alloc((size_t)NN * HD * 4);
    float* sb = (float*)alloc((size_t)NN * HD * 4);
    int* row_start = (int*)alloc((size_t)(NN + 1) * 4);
    int* cnt = (int*)alloc((size_t)NN * 4);
    int* cur = (int*)alloc((size_t)NN * 4);
    int* bsum = (int*)alloc((size_t)SB * 4);
    int* boff = (int*)alloc((size_t)SB * 4);

    // ---- preprocess (once per call) ----
    hipMemsetAsync(cnt, 0, (size_t)NN * 4, stream);
    k_hist<<<(NE + 255) / 256, 256, 0, stream>>>(ei, cnt);
    k_scan1<<<SB, 256, 0, stream>>>(cnt, row_start, bsum);
    k_scan2<<<1, 64, 0, stream>>>(bsum, boff, row_start);
    k_scan3<<<SB, 256, 0, stream>>>(row_start, boff, cur);
    k_scatter<<<(NE + 255) / 256, 256, 0, stream>>>(ei, ea, cur, e5s);

    const int gg64 = 768;               // 3 blocks/CU; ~8 quads per wave-pair
    const int gg10 = (NN + 63) / 64;    // 782
    const int agg_grid = (NN + 3) / 4;  // 12500

    // ---- layer 1 (DIN=10, log1p fused) ----
    k_qkvs10<<<gg10, 256, 0, stream>>>(x, w1q, b1q, w1k, b1k, w1v, b1v, w1s, b1s,
                                       qb, kvb, sb);
    k_agg<false><<<agg_grid, 256, 0, stream>>>(qb, kvb, sb, e5s, w1e, row_start, hb,
                                               lw, lb);

    // ---- layers 2..6 (DIN=64); last layer fuses the output linear ----
    for (int i = 0; i < 5; ++i) {
        k_qkvs64<<<gg64, 256, 0, stream>>>(hb, wq + i * 4096, bq + i * 64,
                                           wk + i * 4096, bk + i * 64,
                                           wv + i * 4096, bv + i * 64,
                                           ws + i * 4096, bs + i * 64,
                                           qb, kvb, sb);
        if (i < 4) {
            k_agg<false><<<agg_grid, 256, 0, stream>>>(qb, kvb, sb, e5s, we + i * 320,
                                                       row_start, hb, lw, lb);
        } else {
            k_agg<true><<<agg_grid, 256, 0, stream>>>(qb, kvb, sb, e5s, we + i * 320,
                                                      row_start, (float*)d_out, lw, lb);
        }
    }
}

// Round 12
// 714.928 us; speedup vs baseline: 1.1416x; 1.0308x over previous
//
#include <hip/hip_runtime.h>
#include <cstdint>
#include <cstddef>

#define NN 50000
#define NE 800000
#define HD 64
#define SB 49  // scan blocks = ceil(50000/1024)

// ---------------- CSR build: histogram ----------------
__global__ void k_hist(const int* __restrict__ ei, int* __restrict__ cnt) {
    int e = blockIdx.x * blockDim.x + threadIdx.x;
    if (e < NE) atomicAdd(&cnt[ei[NE + e]], 1);
}

// ------- hierarchical scan, phase 1: per-block local exclusive scan -------
__global__ __launch_bounds__(256) void k_scan1(const int* __restrict__ cnt,
                                               int* __restrict__ row_start,
                                               int* __restrict__ bsum) {
    __shared__ int ssum[256];
    const int tid = threadIdx.x, b = blockIdx.x;
    const int i0 = b * 1024 + tid * 4;
    int c0 = 0, c1 = 0, c2 = 0, c3 = 0;
    if (i0 + 3 < NN) {
        const int4 c = *(const int4*)(cnt + i0);
        c0 = c.x; c1 = c.y; c2 = c.z; c3 = c.w;
    } else {
        if (i0 + 0 < NN) c0 = cnt[i0 + 0];
        if (i0 + 1 < NN) c1 = cnt[i0 + 1];
        if (i0 + 2 < NN) c2 = cnt[i0 + 2];
        if (i0 + 3 < NN) c3 = cnt[i0 + 3];
    }
    ssum[tid] = c0 + c1 + c2 + c3;
    __syncthreads();
    for (int off = 1; off < 256; off <<= 1) {
        int v = (tid >= off) ? ssum[tid - off] : 0;
        __syncthreads();
        ssum[tid] += v;
        __syncthreads();
    }
    int ex = (tid == 0) ? 0 : ssum[tid - 1];
    if (i0 + 0 < NN) row_start[i0 + 0] = ex;
    ex += c0;
    if (i0 + 1 < NN) row_start[i0 + 1] = ex;
    ex += c1;
    if (i0 + 2 < NN) row_start[i0 + 2] = ex;
    ex += c2;
    if (i0 + 3 < NN) row_start[i0 + 3] = ex;
    if (tid == 255) bsum[b] = ssum[255];
}

// ------- scan phase 2: scan the 49 block sums -------
__global__ __launch_bounds__(64) void k_scan2(const int* __restrict__ bsum,
                                              int* __restrict__ boff,
                                              int* __restrict__ row_start) {
    __shared__ int s[64];
    const int t = threadIdx.x;
    s[t] = (t < SB) ? bsum[t] : 0;
    __syncthreads();
    for (int off = 1; off < 64; off <<= 1) {
        int v = (t >= off) ? s[t - off] : 0;
        __syncthreads();
        s[t] += v;
        __syncthreads();
    }
    if (t < SB) boff[t] = (t == 0) ? 0 : s[t - 1];
    if (t == 0) row_start[NN] = s[SB - 1];  // = NE
}

// ------- scan phase 3: add block offsets; init cur = row_start -------
__global__ __launch_bounds__(256) void k_scan3(int* __restrict__ row_start,
                                               const int* __restrict__ boff,
                                               int* __restrict__ cur) {
    const int b = blockIdx.x;
    const int i0 = b * 1024 + threadIdx.x * 4;
    const int o = boff[b];
#pragma unroll
    for (int k = 0; k < 4; ++k) {
        int i = i0 + k;
        if (i < NN) {
            int v = row_start[i] + o;
            row_start[i] = v;
            cur[i] = v;
        }
    }
}

// ------- CSR scatter: row = [e0..e3, e4, src_byteoff, 0, 0] dst-sorted -------
__global__ void k_scatter(const int* __restrict__ ei, const float* __restrict__ ea,
                          int* __restrict__ cur, float* __restrict__ e5s) {
    int e = blockIdx.x * blockDim.x + threadIdx.x;
    if (e < NE) {
        int d = ei[NE + e];
        int pos = atomicAdd(&cur[d], 1);
        float4 lo;
        lo.x = __logf(ea[e * 5 + 0] + 1.f);
        lo.y = __logf(ea[e * 5 + 1] + 1.f);
        lo.z = __logf(ea[e * 5 + 2] + 1.f);
        lo.w = __logf(ea[e * 5 + 3] + 1.f);
        float4 hi;
        hi.x = __logf(ea[e * 5 + 4] + 1.f);
        hi.y = __int_as_float(ei[e] << 9);  // byte offset into kv (src*512)
        hi.z = 0.f;
        hi.w = 0.f;
        *(float4*)(e5s + (size_t)pos * 8) = lo;
        *(float4*)(e5s + (size_t)pos * 8 + 4) = hi;
    }
}

// ------- fused 4-matrix GEMM, DIN=64: 2-matrix waves, pipelined staging -------
// Grid 768 (3 blocks/CU): each wave loads its 32 KB weight set once and
// amortizes over ~8 quads. half=0 computes q+k (q weights pre-scaled by
// 1/8 so k_agg's logit needs no scaling), half=1 v+s. Broadcast ds_read_b128
// feeds 8 FMAs; wave-private LDS tile, no barriers; next quad's global load
// issued before compute.
__global__ __launch_bounds__(256) void k_qkvs64(
    const float* __restrict__ h,
    const float* __restrict__ Wq, const float* __restrict__ Bq,
    const float* __restrict__ Wk, const float* __restrict__ Bk,
    const float* __restrict__ Wv, const float* __restrict__ Bv,
    const float* __restrict__ Ws, const float* __restrict__ Bs,
    float* __restrict__ qb, float* __restrict__ kvb, float* __restrict__ sb) {
    __shared__ float xs[4][256];
    const int lane = threadIdx.x & 63;
    const int w = threadIdx.x >> 6;
    const int pair = w >> 1, half = w & 1;
    const float* W0 = half ? Wv : Wq;
    const float* B0 = half ? Bv : Bq;
    const float* W1 = half ? Ws : Wk;
    const float* B1 = half ? Bs : Bk;
    float* O0 = half ? (kvb + 64) : qb;
    float* O1 = half ? sb : kvb;
    const int ldo0 = half ? 128 : 64;
    const int ldo1 = half ? 64 : 128;
    const float scl0 = half ? 1.f : 0.125f;  // fold logit scale into q
    float w0[64], w1[64];
#pragma unroll
    for (int j = 0; j < 64; ++j) {
        w0[j] = W0[j * 64 + lane] * scl0;
        w1[j] = W1[j * 64 + lane];
    }
    const float b0 = B0[lane] * scl0, b1 = B1[lane];
    const int nquad = NN / 4;  // 12500
    const int step = gridDim.x * 2;
    int quad = blockIdx.x * 2 + pair;
    if (quad >= nquad) return;
    {
        const float4 g = *(const float4*)(h + (size_t)quad * 256 + lane * 4);
        *(float4*)&xs[w][lane * 4] = g;
    }
    while (true) {
        const int nq = quad + step;
        const bool more = nq < nquad;
        float4 gn;
        if (more) gn = *(const float4*)(h + (size_t)nq * 256 + lane * 4);  // in flight
        float a0[4] = {b0, b0, b0, b0};
        float a1[4] = {b1, b1, b1, b1};
#pragma unroll
        for (int jq = 0; jq < 16; ++jq) {
#pragma unroll
            for (int n = 0; n < 4; ++n) {
                const float4 xv = *(const float4*)&xs[w][n * 64 + jq * 4];  // broadcast
                a0[n] = fmaf(xv.x, w0[jq * 4 + 0], a0[n]);
                a1[n] = fmaf(xv.x, w1[jq * 4 + 0], a1[n]);
                a0[n] = fmaf(xv.y, w0[jq * 4 + 1], a0[n]);
                a1[n] = fmaf(xv.y, w1[jq * 4 + 1], a1[n]);
                a0[n] = fmaf(xv.z, w0[jq * 4 + 2], a0[n]);
                a1[n] = fmaf(xv.z, w1[jq * 4 + 2], a1[n]);
                a0[n] = fmaf(xv.w, w0[jq * 4 + 3], a0[n]);
                a1[n] = fmaf(xv.w, w1[jq * 4 + 3], a1[n]);
            }
        }
#pragma unroll
        for (int n = 0; n < 4; ++n) {
            O0[(size_t)(quad * 4 + n) * ldo0 + lane] = a0[n];
            O1[(size_t)(quad * 4 + n) * ldo1 + lane] = a1[n];
        }
        if (!more) break;
        *(float4*)&xs[w][lane * 4] = gn;  // DS ops in-order: after all tile reads
        quad = nq;
    }
}

// ------- fused 4-matrix GEMM, DIN=10 (layer 1, log1p fused at staging) -------
__global__ __launch_bounds__(256, 4) void k_qkvs10(
    const float* __restrict__ x,
    const float* __restrict__ Wq, const float* __restrict__ Bq,
    const float* __restrict__ Wk, const float* __restrict__ Bk,
    const float* __restrict__ Wv, const float* __restrict__ Bv,
    const float* __restrict__ Ws, const float* __restrict__ Bs,
    float* __restrict__ qb, float* __restrict__ kvb, float* __restrict__ sb) {
    __shared__ float xs[640];
    const int lane = threadIdx.x & 63;
    const int w = threadIdx.x >> 6;
    const float* W = (w == 0) ? Wq : (w == 1) ? Wk : (w == 2) ? Wv : Ws;
    const float* B = (w == 0) ? Bq : (w == 1) ? Bk : (w == 2) ? Bv : Bs;
    float* outp = (w == 0) ? qb : (w == 1) ? kvb : (w == 2) ? (kvb + 64) : sb;
    const int ldo = (w == 1 || w == 2) ? 128 : 64;
    const float scl = (w == 0) ? 0.125f : 1.f;  // fold logit scale into q
    float wr[10];
#pragma unroll
    for (int j = 0; j < 10; ++j) wr[j] = W[j * 64 + lane] * scl;
    const float bias = B[lane] * scl;
    const int tile = blockIdx.x;
    const int fbase = tile * 640;
    const int fcnt = min(640, NN * 10 - fbase);
    if (threadIdx.x * 4 < fcnt) {
        float4 v = *(const float4*)(x + (size_t)fbase + threadIdx.x * 4);
        v.x = __logf(v.x + 1.f);
        v.y = __logf(v.y + 1.f);
        v.z = __logf(v.z + 1.f);
        v.w = __logf(v.w + 1.f);
        *(float4*)&xs[threadIdx.x * 4] = v;
    }
    __syncthreads();
    const int nbase = tile * 64;
    const int nodes = min(64, NN - nbase);
    for (int n = 0; n < nodes; ++n) {
        float acc = bias;
#pragma unroll
        for (int j = 0; j < 10; ++j) acc = fmaf(xs[n * 10 + j], wr[j], acc);
        outp[(size_t)(nbase + n) * ldo + lane] = acc;
    }
}

// ---------------- per-dst-node online-softmax aggregation ----------------
// R10 16x4 structure: one wave per dst node; 4 edges/iter; g = lane>>4 (edge
// slot), t = lane&15. Per-group softmax state + flash merge; 2 exps/iter.
// q arrives pre-scaled by 1/8 from the GEMM. g5 computed group-split: group g
// computes wE-row-g dot (group 0 also row 4), 5 broadcast shfls share.
// FINAL folds the output linear.
template <bool FINAL>
__global__ __launch_bounds__(256) void k_agg(
    const float* __restrict__ q, const float* __restrict__ kv,
    const float* __restrict__ sk, const float* __restrict__ e5s,
    const float* __restrict__ wE, const int* __restrict__ row_start,
    float* __restrict__ hout, const float* __restrict__ lw, const float* lb) {
    const int lane = threadIdx.x & 63;
    const int g = lane >> 4, t = lane & 15;
    const int node = __builtin_amdgcn_readfirstlane(blockIdx.x * 4 + (threadIdx.x >> 6));
    if (node >= NN) return;
    const int beg = row_start[node], end = row_start[node + 1];
    if (beg == end) {
        const float4 s4 = *(const float4*)(sk + (size_t)node * 64 + t * 4);
        if (FINAL) {
            const float4 lw4 = *(const float4*)(lw + t * 4);
            float r = s4.x * lw4.x;
            r = fmaf(s4.y, lw4.y, r);
            r = fmaf(s4.z, lw4.z, r);
            r = fmaf(s4.w, lw4.w, r);
            r += __shfl_xor(r, 1);
            r += __shfl_xor(r, 2);
            r += __shfl_xor(r, 4);
            r += __shfl_xor(r, 8);
            if (lane == 0) hout[node] = r + lb[0];
        } else if (g == 0) {
            *(float4*)(hout + (size_t)node * 64 + t * 4) = s4;
        }
        return;
    }
    const float4 q4 = *(const float4*)(q + (size_t)node * 64 + t * 4);  // pre-scaled
    // g5: group g computes dot64(q, wE row g); group 0 also row 4; broadcast.
    float g5[5];
    {
        const float4 wg = *(const float4*)(wE + g * 64 + t * 4);
        float dc = q4.x * wg.x;
        dc = fmaf(q4.y, wg.y, dc);
        dc = fmaf(q4.z, wg.z, dc);
        dc = fmaf(q4.w, wg.w, dc);
        dc += __shfl_xor(dc, 1);
        dc += __shfl_xor(dc, 2);
        dc += __shfl_xor(dc, 4);
        dc += __shfl_xor(dc, 8);
        const float4 w4 = *(const float4*)(wE + 4 * 64 + t * 4);
        float d4 = q4.x * w4.x;
        d4 = fmaf(q4.y, w4.y, d4);
        d4 = fmaf(q4.z, w4.z, d4);
        d4 = fmaf(q4.w, w4.w, d4);
        d4 += __shfl_xor(d4, 1);
        d4 += __shfl_xor(d4, 2);
        d4 += __shfl_xor(d4, 4);
        d4 += __shfl_xor(d4, 8);
        g5[0] = __shfl(dc, 0);
        g5[1] = __shfl(dc, 16);
        g5[2] = __shfl(dc, 32);
        g5[3] = __shfl(dc, 48);
        g5[4] = __shfl(d4, 0);
    }
    // per-group online-softmax state
    float m = -1e30f, l = 0.f;
    float4 accv = {0.f, 0.f, 0.f, 0.f};
    float a50 = 0.f, a51 = 0.f, a52 = 0.f, a53 = 0.f, a54 = 0.f;
    const char* kvc = (const char*)kv;
    // pipeline preamble: e5 2-deep, kv 1-deep
    const int i0x = beg + g;
    const int i0 = (i0x < end) ? i0x : beg;
    float4 e0lo = *(const float4*)(e5s + (size_t)i0 * 8);
    float2 e0hi = *(const float2*)(e5s + (size_t)i0 * 8 + 4);
    const int i1x = beg + 4 + g;
    const int i1 = (i1x < end) ? i1x : beg;
    float4 e1lo = *(const float4*)(e5s + (size_t)i1 * 8);
    float2 e1hi = *(const float2*)(e5s + (size_t)i1 * 8 + 4);
    const float* kp0 = (const float*)(kvc + (size_t)(unsigned)__float_as_int(e0hi.y)) + t * 4;
    float4 k4 = *(const float4*)(kp0);
    float4 v4 = *(const float4*)(kp0 + 64);
#pragma unroll 2
    for (int p = beg; p < end; p += 4) {
        // e5 prefetch for iter p+8 (sequential, L2-friendly)
        const int nx = p + 8 + g;
        const int npp = (nx < end) ? nx : beg;
        const float4 nlo = *(const float4*)(e5s + (size_t)npp * 8);
        const float2 nhi = *(const float2*)(e5s + (size_t)npp * 8 + 4);
        // kv gather for iter p+4 (e1 landed one iter ago)
        const float* kpn =
            (const float*)(kvc + (size_t)(unsigned)__float_as_int(e1hi.y)) + t * 4;
        const float4 nk4 = *(const float4*)(kpn);
        const float4 nv4 = *(const float4*)(kpn + 64);
        // compute current edge
        const bool act = (p + g) < end;
        float d = q4.x * k4.x;
        d = fmaf(q4.y, k4.y, d);
        d = fmaf(q4.z, k4.z, d);
        d = fmaf(q4.w, k4.w, d);
        d += __shfl_xor(d, 1);
        d += __shfl_xor(d, 2);
        d += __shfl_xor(d, 4);
        d += __shfl_xor(d, 8);
        float d5 = g5[0] * e0lo.x;
        d5 = fmaf(g5[1], e0lo.y, d5);
        d5 = fmaf(g5[2], e0lo.z, d5);
        d5 = fmaf(g5[3], e0lo.w, d5);
        d5 = fmaf(g5[4], e0hi.x, d5);
        const float la = act ? (d + d5) : -1e30f;
        const float nm = fmaxf(m, la);
        const float scl = __expf(m - nm);
        const float pa = __expf(la - nm);
        l = fmaf(l, scl, pa);
        accv.x = fmaf(accv.x, scl, pa * v4.x);
        accv.y = fmaf(accv.y, scl, pa * v4.y);
        accv.z = fmaf(accv.z, scl, pa * v4.z);
        accv.w = fmaf(accv.w, scl, pa * v4.w);
        a50 = fmaf(a50, scl, pa * e0lo.x);
        a51 = fmaf(a51, scl, pa * e0lo.y);
        a52 = fmaf(a52, scl, pa * e0lo.z);
        a53 = fmaf(a53, scl, pa * e0lo.w);
        a54 = fmaf(a54, scl, pa * e0hi.x);
        m = nm;
        // rotate pipeline
        e0lo = e1lo;
        e0hi = e1hi;
        e1lo = nlo;
        e1hi = nhi;
        k4 = nk4;
        v4 = nv4;
    }
    // ---- merge the 4 per-group states (flash-style) ----
    float M = fmaxf(m, __shfl_xor(m, 16));
    M = fmaxf(M, __shfl_xor(M, 32));
    const float f = __expf(m - M);  // 0 for never-active groups
    float lz = l * f;
    lz += __shfl_xor(lz, 16);
    lz += __shfl_xor(lz, 32);
    accv.x *= f;
    accv.y *= f;
    accv.z *= f;
    accv.w *= f;
    a50 *= f;
    a51 *= f;
    a52 *= f;
    a53 *= f;
    a54 *= f;
#pragma unroll
    for (int s = 16; s <= 32; s <<= 1) {
        accv.x += __shfl_xor(accv.x, s);
        accv.y += __shfl_xor(accv.y, s);
        accv.z += __shfl_xor(accv.z, s);
        accv.w += __shfl_xor(accv.w, s);
        a50 += __shfl_xor(a50, s);
        a51 += __shfl_xor(a51, s);
        a52 += __shfl_xor(a52, s);
        a53 += __shfl_xor(a53, s);
        a54 += __shfl_xor(a54, s);
    }
    // fold edge-feature accumulator back through wE; add skip
    float4 t4 = accv;
    {
        const float4 w0 = *(const float4*)(wE + 0 * 64 + t * 4);
        const float4 w1 = *(const float4*)(wE + 1 * 64 + t * 4);
        const float4 w2 = *(const float4*)(wE + 2 * 64 + t * 4);
        const float4 w3 = *(const float4*)(wE + 3 * 64 + t * 4);
        const float4 w4r = *(const float4*)(wE + 4 * 64 + t * 4);
        t4.x = fmaf(a50, w0.x, t4.x);
        t4.y = fmaf(a50, w0.y, t4.y);
        t4.z = fmaf(a50, w0.z, t4.z);
        t4.w = fmaf(a50, w0.w, t4.w);
        t4.x = fmaf(a51, w1.x, t4.x);
        t4.y = fmaf(a51, w1.y, t4.y);
        t4.z = fmaf(a51, w1.z, t4.z);
        t4.w = fmaf(a51, w1.w, t4.w);
        t4.x = fmaf(a52, w2.x, t4.x);
        t4.y = fmaf(a52, w2.y, t4.y);
        t4.z = fmaf(a52, w2.z, t4.z);
        t4.w = fmaf(a52, w2.w, t4.w);
        t4.x = fmaf(a53, w3.x, t4.x);
        t4.y = fmaf(a53, w3.y, t4.y);
        t4.z = fmaf(a53, w3.z, t4.z);
        t4.w = fmaf(a53, w3.w, t4.w);
        t4.x = fmaf(a54, w4r.x, t4.x);
        t4.y = fmaf(a54, w4r.y, t4.y);
        t4.z = fmaf(a54, w4r.z, t4.z);
        t4.w = fmaf(a54, w4r.w, t4.w);
    }
    const float4 s4 = *(const float4*)(sk + (size_t)node * 64 + t * 4);
    const float rl = 1.f / lz;
    float4 o;
    o.x = fmaf(t4.x, rl, s4.x);
    o.y = fmaf(t4.y, rl, s4.y);
    o.z = fmaf(t4.z, rl, s4.z);
    o.w = fmaf(t4.w, rl, s4.w);
    if (FINAL) {
        const float4 lw4 = *(const float4*)(lw + t * 4);
        float r = o.x * lw4.x;
        r = fmaf(o.y, lw4.y, r);
        r = fmaf(o.z, lw4.z, r);
        r = fmaf(o.w, lw4.w, r);
        r += __shfl_xor(r, 1);
        r += __shfl_xor(r, 2);
        r += __shfl_xor(r, 4);
        r += __shfl_xor(r, 8);
        if (lane == 0) hout[node] = r + lb[0];
    } else if (g == 0) {
        *(float4*)(hout + (size_t)node * 64 + t * 4) = o;
    }
}

extern "C" void kernel_launch(void* const* d_in, const int* in_sizes, int n_in,
                              void* d_out, int out_size, void* d_ws, size_t ws_size,
                              hipStream_t stream) {
    const float* x = (const float*)d_in[0];
    const int* ei = (const int*)d_in[1];
    const float* ea = (const float*)d_in[2];
    const float* w1q = (const float*)d_in[3];
    const float* b1q = (const float*)d_in[4];
    const float* w1k = (const float*)d_in[5];
    const float* b1k = (const float*)d_in[6];
    const float* w1v = (const float*)d_in[7];
    const float* b1v = (const float*)d_in[8];
    const float* w1e = (const float*)d_in[9];
    const float* w1s = (const float*)d_in[10];
    const float* b1s = (const float*)d_in[11];
    const float* wq = (const float*)d_in[12];
    const float* bq = (const float*)d_in[13];
    const float* wk = (const float*)d_in[14];
    const float* bk = (const float*)d_in[15];
    const float* wv = (const float*)d_in[16];
    const float* bv = (const float*)d_in[17];
    const float* we = (const float*)d_in[18];
    const float* ws = (const float*)d_in[19];
    const float* bs = (const float*)d_in[20];
    const float* lw = (const float*)d_in[21];
    const float* lb = (const float*)d_in[22];

    // ---- workspace carve (256B aligned), ~90 MB ----
    uintptr_t p = (uintptr_t)d_ws;
    auto alloc = [&](size_t bytes) -> void* {
        void* r = (void*)p;
        p += (bytes + 255) & ~(size_t)255;
        return r;
    };
    float* e5s = (float*)alloc((size_t)NE * 8 * 4);    // 25.6 MB, dst-sorted rows
    float* hb = (float*)alloc((size_t)NN * HD * 4);    // 12.8 MB
    float* kvb = (float*)alloc((size_t)NN * 128 * 4);  // 25.6 MB interleaved k|v
    float* qb = (float*)alloc((size_t)NN * HD * 4);
    float* sb = (float*)alloc((size_t)NN * HD * 4);
    int* row_start = (int*)alloc((size_t)(NN + 1) * 4);
    int* cnt = (int*)alloc((size_t)NN * 4);
    int* cur = (int*)alloc((size_t)NN * 4);
    int* bsum = (int*)alloc((size_t)SB * 4);
    int* boff = (int*)alloc((size_t)SB * 4);

    // ---- preprocess (once per call) ----
    hipMemsetAsync(cnt, 0, (size_t)NN * 4, stream);
    k_hist<<<(NE + 255) / 256, 256, 0, stream>>>(ei, cnt);
    k_scan1<<<SB, 256, 0, stream>>>(cnt, row_start, bsum);
    k_scan2<<<1, 64, 0, stream>>>(bsum, boff, row_start);
    k_scan3<<<SB, 256, 0, stream>>>(row_start, boff, cur);
    k_scatter<<<(NE + 255) / 256, 256, 0, stream>>>(ei, ea, cur, e5s);

    const int gg64 = 768;               // 3 blocks/CU; ~8 quads per wave-pair
    const int gg10 = (NN + 63) / 64;    // 782
    const int agg_grid = (NN + 3) / 4;  // 12500

    // ---- layer 1 (DIN=10, log1p fused) ----
    k_qkvs10<<<gg10, 256, 0, stream>>>(x, w1q, b1q, w1k, b1k, w1v, b1v, w1s, b1s,
                                       qb, kvb, sb);
    k_agg<false><<<agg_grid, 256, 0, stream>>>(qb, kvb, sb, e5s, w1e, row_start, hb,
                                               lw, lb);

    // ---- layers 2..6 (DIN=64); last layer fuses the output linear ----
    for (int i = 0; i < 5; ++i) {
        k_qkvs64<<<gg64, 256, 0, stream>>>(hb, wq + i * 4096, bq + i * 64,
                                           wk + i * 4096, bk + i * 64,
                                           wv + i * 4096, bv + i * 64,
                                           ws + i * 4096, bs + i * 64,
                                           qb, kvb, sb);
        if (i < 4) {
            k_agg<false><<<agg_grid, 256, 0, stream>>>(qb, kvb, sb, e5s, we + i * 320,
                                                       row_start, hb, lw, lb);
        } else {
            k_agg<true><<<agg_grid, 256, 0, stream>>>(qb, kvb, sb, e5s, we + i * 320,
                                                      row_start, (float*)d_out, lw, lb);
        }
    }
}